// Round 13
// baseline (174.543 us; speedup 1.0000x reference)
//
#include <hip/hip_runtime.h>
#include <hip/hip_bf16.h>
#include <stdint.h>

// Problem constants: B=2, M=8192, D=1024, H=16, hd=64, SEG=2048, DIL=8
// => S=4 segments, Kn=256 dilated keys/segment, nb=32 query blocks of 64.

typedef __attribute__((ext_vector_type(8))) short short8;
typedef __attribute__((ext_vector_type(4))) float f32x4;
typedef __attribute__((ext_vector_type(4))) unsigned short ushort4v;

#define DEVI static __device__ __forceinline__

DEVI unsigned short f2bf(float f) {
  union { float f; uint32_t u; } v; v.f = f;
  return (unsigned short)((v.u + 0x7FFFu + ((v.u >> 16) & 1u)) >> 16);
}

// RNE pair pack (epilogue-quality).
DEVI uint32_t pack_bf16(float lo, float hi) {
  return (uint32_t)f2bf(lo) | ((uint32_t)f2bf(hi) << 16);
}

// Round-half-up pair pack (hot paths): 5 VALU ops vs ~10. Differs from RNE
// only on exact ties (half-ulp) -> negligible absmax shift.
DEVI uint32_t pack_hu(float lo, float hi) {
  union { float f; uint32_t u; } a, b; a.f = lo; b.f = hi;
  return ((a.u + 0x8000u) >> 16) | ((b.u + 0x8000u) & 0xFFFF0000u);
}

DEVI void gload_lds16(const void* g, void* l) {
  __builtin_amdgcn_global_load_lds((const __attribute__((address_space(1))) void*)g,
                                   (__attribute__((address_space(3))) void*)l,
                                   16, 0, 0);
}

// f32x8 -> 4 packed u32 (16B) for LDS staging
DEVI uint4 cvt8_hu(float4 x, float4 y) {
  uint4 r;
  r.x = pack_hu(x.x, x.y); r.y = pack_hu(x.z, x.w);
  r.z = pack_hu(y.x, y.y); r.w = pack_hu(y.z, y.w);
  return r;
}

// ---------------- f32 -> bf16 convert (weights only now) ----------------
__global__ void cvt_kernel(const float* __restrict__ in, unsigned short* __restrict__ out, int n) {
  int i = (blockIdx.x * 256 + threadIdx.x) * 4;
  if (i >= n) return;
  float4 f = *(const float4*)(in + i);
  uint2 o;
  o.x = (uint32_t)f2bf(f.x) | ((uint32_t)f2bf(f.y) << 16);
  o.y = (uint32_t)f2bf(f.z) | ((uint32_t)f2bf(f.w) << 16);
  *(uint2*)(out + i) = o;
}

// ======== 8-phase 256x256 GEMM (r12 schedule) + optional f32-A fusion ========
// A_F32=false: exact r12 kernel (A via gload_lds; waits vmcnt(4) @ p0,p3,p4,p7).
// A_F32=true: A staged f32->bf16 in-register (issue f32 loads, then B-gloads,
// then convert -- the compiler's convert-wait drains A and leaves B gloads
// outstanding). My end-of-phase waits then count ONLY B-gloads: vmcnt(2) @
// p0,p3,p4,p7; tail t=7: p0/p3 vmcnt(2), p4 vmcnt(0). Per-unit retire and
// overwrite margins re-derived for this variant (A writes are synchronous
// ds_writes >=4 barriers after the dest's last reader; B0'/B1' retired by
// the p2/p4 convert-waits or the counted vmcnt before first read).
template<bool A_F32, bool OUT_F32>
__global__ __launch_bounds__(512, 1) void gemm8p(
    const void* __restrict__ Av, const unsigned short* __restrict__ B,
    void* __restrict__ Cv, float scale)
{
  __shared__ unsigned short smA[2][2][128 * 64];   // [buf][half][r][k] swizzled
  __shared__ unsigned short smB[2][2][128 * 64];
  const int tid = threadIdx.x;
  const int tm = blockIdx.x, tn = blockIdx.y;
  const int w = tid >> 6, lane = tid & 63;
  const int wm = w >> 2, wn = w & 3;
  const int lr = lane & 15, lq = lane >> 4;

  const int e0 = tid * 8,        e1 = (512 + tid) * 8;
  const int srow0 = e0 >> 6,     srow1 = e1 >> 6;
  const int sc0 = (e0 >> 3) & 7, sc1 = (e1 >> 3) & 7;
  const int scol0 = (sc0 ^ (srow0 & 7)) * 8, scol1 = (sc1 ^ (srow1 & 7)) * 8;
  const int se0 = e0, se1 = e1;

  const unsigned short* Ab16 = (const unsigned short*)Av + (long)tm * 256 * 1024;
  const float*          Ab32 = (const float*)Av + (long)tm * 256 * 1024;
  const unsigned short* Bbase = B + (long)tn * 256 * 1024;

  auto stage_a = [&](int bf, int hf, int kt) {
    if constexpr (A_F32) {
      const float* s0 = Ab32 + (long)(hf * 128 + srow0) * 1024 + kt * 64 + scol0;
      const float* s1 = Ab32 + (long)(hf * 128 + srow1) * 1024 + kt * 64 + scol1;
      float4 x0 = *(const float4*)s0, y0 = *(const float4*)(s0 + 4);
      float4 x1 = *(const float4*)s1, y1 = *(const float4*)(s1 + 4);
      *(uint4*)&smA[bf][hf][se0] = cvt8_hu(x0, y0);
      *(uint4*)&smA[bf][hf][se1] = cvt8_hu(x1, y1);
    } else {
      gload_lds16(Ab16 + (long)(hf * 128 + srow0) * 1024 + kt * 64 + scol0, &smA[bf][hf][se0]);
      gload_lds16(Ab16 + (long)(hf * 128 + srow1) * 1024 + kt * 64 + scol1, &smA[bf][hf][se1]);
    }
  };
  auto stage_b = [&](int bf, int hf, int kt) {
    gload_lds16(Bbase + (long)(hf * 128 + srow0) * 1024 + kt * 64 + scol0, &smB[bf][hf][se0]);
    gload_lds16(Bbase + (long)(hf * 128 + srow1) * 1024 + kt * 64 + scol1, &smB[bf][hf][se1]);
  };

  f32x4 acc[8][4] = {};
  short8 af[4][2];        // current A-half fragments (persist 2 phases)
  short8 bfr[2][2][2];    // BOTH B-half fragments [half][nj2][kk]

  // prologue: tile 0 into buf0. f32 mode: B-gloads first, then sync A converts.
  stage_b(0, 0, 0); stage_b(0, 1, 0);
  stage_a(0, 0, 0); stage_a(0, 1, 0);
  if constexpr (A_F32) asm volatile("s_waitcnt vmcnt(2)" ::: "memory");
  else                 asm volatile("s_waitcnt vmcnt(4)" ::: "memory");
  __builtin_amdgcn_s_barrier();
  asm volatile("" ::: "memory");

  for (int t = 0; t < 8; ++t) {
#pragma unroll
    for (int p = 0; p < 8; ++p) {
      const int o = p >> 2;            // LDS buf: 0 for kt=2t, 1 for kt=2t+1
      const int q = p & 3;
      const int a = (p >> 1) & 1;      // A-half: 0,0,1,1
      const int b = a ^ (q & 1);       // B-half: 0,1,1,0 (gray)

      // ---- ds_read only NEW fragments for this phase
      if (q == 0 || q == 2) {          // new A-half (8 x b128)
#pragma unroll
        for (int mi2 = 0; mi2 < 4; ++mi2) {
          int r = wm * 64 + mi2 * 16 + lr;
#pragma unroll
          for (int kk = 0; kk < 2; ++kk) {
            int kc = kk * 4 + lq;
            af[mi2][kk] = *(const short8*)&smA[o][a][r * 64 + ((kc ^ (r & 7)) * 8)];
          }
        }
      }
      if (q == 0 || q == 1) {          // new B-half b (4 x b128), kept resident
#pragma unroll
        for (int nj2 = 0; nj2 < 2; ++nj2) {
          int r = wn * 32 + nj2 * 16 + lr;
#pragma unroll
          for (int kk = 0; kk < 2; ++kk) {
            int kc = kk * 4 + lq;
            bfr[b][nj2][kk] = *(const short8*)&smB[o][b][r * 64 + ((kc ^ (r & 7)) * 8)];
          }
        }
      }

      // ---- batch stage at p0,p2,p4,p6 (B-gloads issued before A convert)
      switch (p) {
        case 0: stage_b(1, 0, 2 * t + 1); stage_a(1, 0, 2 * t + 1); break;
        case 2: stage_b(1, 1, 2 * t + 1); stage_a(1, 1, 2 * t + 1); break;
        case 4: if (t < 7) { stage_b(0, 0, 2 * t + 2); stage_a(0, 0, 2 * t + 2); } break;
        case 6: if (t < 7) { stage_b(0, 1, 2 * t + 2); stage_a(0, 1, 2 * t + 2); } break;
      }

      // ---- first barrier; drain ds_reads; MFMA
      __builtin_amdgcn_s_barrier();
      if (q != 3) {
        asm volatile("s_waitcnt lgkmcnt(0)" ::: "memory");
        __builtin_amdgcn_sched_barrier(0);
      }

      __builtin_amdgcn_s_setprio(1);
#pragma unroll
      for (int kk = 0; kk < 2; ++kk)
#pragma unroll
        for (int mi2 = 0; mi2 < 4; ++mi2)
#pragma unroll
          for (int nj2 = 0; nj2 < 2; ++nj2)
            acc[a * 4 + mi2][b * 2 + nj2] = __builtin_amdgcn_mfma_f32_16x16x32_bf16(
                af[mi2][kk], bfr[b][nj2][kk], acc[a * 4 + mi2][b * 2 + nj2], 0, 0, 0);
      __builtin_amdgcn_s_setprio(0);

      // ---- counted wait (p0,p3,p4,p7) + second barrier
      if (t < 7) {
        if (p == 0 || p == 3 || p == 4 || p == 7) {
          if constexpr (A_F32) asm volatile("s_waitcnt vmcnt(2)" ::: "memory");
          else                 asm volatile("s_waitcnt vmcnt(4)" ::: "memory");
        }
      } else {
        if (p == 0 || p == 3) {
          if constexpr (A_F32) asm volatile("s_waitcnt vmcnt(2)" ::: "memory");
          else                 asm volatile("s_waitcnt vmcnt(4)" ::: "memory");
        } else if (p == 4) {
          asm volatile("s_waitcnt vmcnt(0)" ::: "memory");
        }
      }
      __builtin_amdgcn_s_barrier();
      asm volatile("" ::: "memory");
    }
  }

  // ---- epilogue
  const int row0 = tm * 256 + wm * 64 + lq * 4;
  const int col0 = tn * 256 + wn * 32 + lr;
#pragma unroll
  for (int mi = 0; mi < 8; ++mi) {
    int row = row0 + (mi & 3) * 16 + (mi >> 2) * 128;
#pragma unroll
    for (int nj = 0; nj < 4; ++nj) {
      int col = col0 + (nj & 1) * 16 + (nj >> 1) * 128;
#pragma unroll
      for (int rr = 0; rr < 4; ++rr) {
        float v = acc[mi][nj][rr] * scale;
        long off = (long)(row + rr) * 1024 + col;
        if (OUT_F32) ((float*)Cv)[off] = v;
        else         ((unsigned short*)Cv)[off] = f2bf(v);
      }
    }
  }
}

// ---------------- 128^2 GEMM for the KV split (f32 A from x) ----------------
// A: f32, row m at A + m*8192 (dilated rows of x). __syncthreads drains vmcnt
// (compiler emits vmcnt(0) lgkmcnt(0) before s_barrier) so B gload_lds is safe.
// EPI 2: tn<8 -> bf16 K rows to Cv; tn>=8 -> V TRANSPOSED + sigma-permuted to
// Cv2 (row = seg*1024+f; u32 col c packs tokens (32*(c>>4)+(c&15), +16)).
template<int EPI>
__global__ __launch_bounds__(256, 2) void gemm_bt(
    const float* __restrict__ A, const unsigned short* __restrict__ B,
    void* __restrict__ Cv, unsigned short* __restrict__ Cv2,
    float scale, long a_row_stride, int ldc, int K)
{
  __shared__ unsigned short smA[128 * 64];
  __shared__ unsigned short smB[128 * 64];
  const int tid = threadIdx.x;
  const int tm = blockIdx.x, tn = blockIdx.y;
  const int w = tid >> 6, lane = tid & 63;
  const int wr = (w >> 1) * 64, wc = (w & 1) * 64;
  const int lr = lane & 15, lq = lane >> 4;

  int se[4], srow[4], scol[4];
#pragma unroll
  for (int i = 0; i < 4; ++i) {
    int e = (i * 256 + tid) * 8;
    int r = e >> 6;
    int cc = (e >> 3) & 7;
    se[i] = e; srow[i] = r; scol[i] = (cc ^ (r & 7)) * 8;
  }

  f32x4 acc[4][4] = {};

  for (int kt = 0; kt < K / 64; ++kt) {
    if (kt) __syncthreads();
#pragma unroll
    for (int i = 0; i < 4; ++i) {
      const float* s = A + (long)(tm * 128 + srow[i]) * a_row_stride + kt * 64 + scol[i];
      float4 x0 = *(const float4*)s, y0 = *(const float4*)(s + 4);
      *(uint4*)&smA[se[i]] = cvt8_hu(x0, y0);
    }
#pragma unroll
    for (int i = 0; i < 4; ++i)
      gload_lds16(B + (long)(tn * 128 + srow[i]) * K + kt * 64 + scol[i], &smB[se[i]]);
    __syncthreads();

#pragma unroll
    for (int kk = 0; kk < 2; ++kk) {
      int kc = kk * 4 + lq;
      short8 af[4], bfm[4];
#pragma unroll
      for (int i = 0; i < 4; ++i) {
        int row = wr + i * 16 + lr;
        af[i] = *(const short8*)&smA[row * 64 + ((kc ^ (row & 7)) * 8)];
      }
#pragma unroll
      for (int j = 0; j < 4; ++j) {
        int row = wc + j * 16 + lr;
        bfm[j] = *(const short8*)&smB[row * 64 + ((kc ^ (row & 7)) * 8)];
      }
#pragma unroll
      for (int i = 0; i < 4; ++i)
#pragma unroll
        for (int j = 0; j < 4; ++j)
          acc[i][j] = __builtin_amdgcn_mfma_f32_16x16x32_bf16(af[i], bfm[j], acc[i][j], 0, 0, 0);
    }
  }

  if (EPI == 2 && tn >= 8) {
    const int fbase = (tn - 8) * 128 + wc;
#pragma unroll
    for (int ip = 0; ip < 4; ip += 2) {
      int t0 = tm * 128 + wr + ip * 16 + lq * 4;
      int seg = t0 >> 8;
      int ts  = t0 & 255;
      int c32 = (ts >> 5) * 16 + (ts & 15);
#pragma unroll
      for (int j = 0; j < 4; ++j) {
        int f = fbase + j * 16 + lr;
        uint32_t* rp = (uint32_t*)&Cv2[((long)(seg * 1024 + f)) * 256];
        uint4 U;
        U.x = pack_bf16(acc[ip][j][0] * scale, acc[ip + 1][j][0] * scale);
        U.y = pack_bf16(acc[ip][j][1] * scale, acc[ip + 1][j][1] * scale);
        U.z = pack_bf16(acc[ip][j][2] * scale, acc[ip + 1][j][2] * scale);
        U.w = pack_bf16(acc[ip][j][3] * scale, acc[ip + 1][j][3] * scale);
        *(uint4*)&rp[c32] = U;
      }
    }
    return;
  }

#pragma unroll
  for (int i = 0; i < 4; ++i) {
    int rg0 = tm * 128 + wr + i * 16 + lq * 4;
#pragma unroll
    for (int j = 0; j < 4; ++j) {
      int cg = tn * 128 + wc + j * 16 + lr;
#pragma unroll
      for (int r = 0; r < 4; ++r) {
        float v = acc[i][j][r] * scale;
        long off = (long)(rg0 + r) * ldc + cg;
        if (EPI == 0) ((float*)Cv)[off] = v;
        else          ((unsigned short*)Cv)[off] = f2bf(v);
      }
    }
  }
}

// ---------------- segment-local dilated attention, 2-deep pipeline ----------
// (r11/r12 structure; softmax pack now round-half-up, epilogue packed stores)
__global__ __launch_bounds__(512, 2) void attn_kernel(
    const unsigned short* __restrict__ qb,    // [16384][1024] bf16, q*scale
    const unsigned short* __restrict__ kb,    // [2048][1024] bf16 dilated keys
    const unsigned short* __restrict__ vtb,   // sigma-permuted V^T
    unsigned short* __restrict__ attout)      // [16384][1024] bf16, col = h*64+d
{
  __shared__ unsigned short v_t[64 * 256];    // [f][g] swizzled, 32 KB
  __shared__ uint32_t w32[8][64][20];         // per-wave [q][col] slices, 40 KB

  const int u = (blockIdx.x & 7) * 64 + (blockIdx.x >> 3);
  const int quarter = u & 3, h = (u >> 2) & 15, s = (u >> 6) & 3, b = u >> 8;
  const int tid = threadIdx.x, w = tid >> 6, lane = tid & 63;
  const int lr = lane & 15, lq = lane >> 4;
  const long qrow0 = (long)b * 8192 + s * 2048 + quarter * 512 + w * 64;
  const int hc = h * 64;

  const unsigned short* kbase = kb + ((long)(b * 4 + s) * 256) * 1024 + hc;
  const unsigned short* vbase = vtb + ((long)(b * 4 + s) * 1024 + hc) * 256;

#pragma unroll
  for (int it = 0; it < 4; ++it) {
    int e = (it * 512 + tid) * 8;
    int f = e >> 8;
    int ch = (e >> 3) & 31;
    gload_lds16(vbase + (long)f * 256 + ((ch ^ (f & 7)) * 8), &v_t[e]);
  }

  const unsigned short* qbase = qb + qrow0 * 1024 + hc;
  short8 aq[4][2];
#pragma unroll
  for (int i = 0; i < 4; ++i)
#pragma unroll
    for (int kk = 0; kk < 2; ++kk)
      aq[i][kk] = *(const short8*)&qbase[(i * 16 + lr) * 1024 + (kk * 4 + lq) * 8];

  __syncthreads();   // V staged (only barrier in the kernel)

  short8 ones;
#pragma unroll
  for (int e = 0; e < 8; ++e) ones[e] = (short)0x3F80;  // bf16 1.0

  uint32_t (*wsl)[20] = w32[w];

  f32x4 acc_pv[4][4] = {};
  f32x4 acc_den[4] = {};
  short8 bk0[2][2], bk1[2][2];
  f32x4 sA[4][2], sB[4][2];

#define LOADK(BK, CC) do { \
  _Pragma("unroll") for (int j = 0; j < 2; ++j) \
    _Pragma("unroll") for (int kk = 0; kk < 2; ++kk) \
      BK[j][kk] = *(const short8*)&kbase[(long)((CC) * 32 + j * 16 + lr) * 1024 + (kk * 4 + lq) * 8]; \
} while (0)

#define QKT(S, BK) do { \
  _Pragma("unroll") for (int i = 0; i < 4; ++i) \
    _Pragma("unroll") for (int j = 0; j < 2; ++j) { \
      f32x4 z = {0.f, 0.f, 0.f, 0.f}; S[i][j] = z; } \
  _Pragma("unroll") for (int kk = 0; kk < 2; ++kk) \
    _Pragma("unroll") for (int i = 0; i < 4; ++i) \
      _Pragma("unroll") for (int j = 0; j < 2; ++j) \
        S[i][j] = __builtin_amdgcn_mfma_f32_16x16x32_bf16(aq[i][kk], BK[j][kk], S[i][j], 0, 0, 0); \
} while (0)

#define SOFTPV(S, CC) do { \
  float c0 = -3.4e38f, c1 = -3.4e38f; \
  _Pragma("unroll") for (int i = 0; i < 4; ++i) \
    _Pragma("unroll") for (int r = 0; r < 4; ++r) { \
      c0 = fmaxf(c0, S[i][0][r]); c1 = fmaxf(c1, S[i][1][r]); } \
  c0 = fmaxf(c0, __shfl_xor(c0, 16)); c0 = fmaxf(c0, __shfl_xor(c0, 32)); \
  c1 = fmaxf(c1, __shfl_xor(c1, 16)); c1 = fmaxf(c1, __shfl_xor(c1, 32)); \
  _Pragma("unroll") for (int i = 0; i < 4; ++i) \
    _Pragma("unroll") for (int r = 0; r < 4; ++r) { \
      int qq = i * 16 + lq * 4 + r; \
      wsl[qq][lr] = pack_hu(__expf(S[i][0][r] - c0), __expf(S[i][1][r] - c1)); } \
  short8 av_[4]; \
  _Pragma("unroll") for (int ct = 0; ct < 4; ++ct) { \
    int frow = ct * 16 + lr; \
    av_[ct] = *(const short8*)&v_t[frow * 256 + ((((CC) * 4 + lq) ^ (frow & 7)) << 3)]; } \
  _Pragma("unroll") for (int qi = 0; qi < 4; ++qi) { \
    short8 bw = *(const short8*)&wsl[qi * 16 + lr][lq * 4]; \
    acc_den[qi] = __builtin_amdgcn_mfma_f32_16x16x32_bf16(ones, bw, acc_den[qi], 0, 0, 0); \
    _Pragma("unroll") for (int ct = 0; ct < 4; ++ct) \
      acc_pv[qi][ct] = __builtin_amdgcn_mfma_f32_16x16x32_bf16(av_[ct], bw, acc_pv[qi][ct], 0, 0, 0); } \
} while (0)

  // prologue: K chunks 0,1 in regs; scores for chunk 0
  LOADK(bk0, 0);
  LOADK(bk1, 1);
  QKT(sA, bk0);

  // 2-deep pipeline, unrolled (named banks; no runtime indexing)
  LOADK(bk0, 2); QKT(sB, bk1); SOFTPV(sA, 0);
  LOADK(bk1, 3); QKT(sA, bk0); SOFTPV(sB, 1);
  LOADK(bk0, 4); QKT(sB, bk1); SOFTPV(sA, 2);
  LOADK(bk1, 5); QKT(sA, bk0); SOFTPV(sB, 3);
  LOADK(bk0, 6); QKT(sB, bk1); SOFTPV(sA, 4);
  LOADK(bk1, 7); QKT(sA, bk0); SOFTPV(sB, 5);
                 QKT(sB, bk1); SOFTPV(sA, 6);
                               SOFTPV(sB, 7);

  // ---- epilogue: out[q][f] = num/den, packed 8B stores
#pragma unroll
  for (int qi = 0; qi < 4; ++qi) {
    float inv = 1.0f / (acc_den[qi][0] + 1e-10f);
    long orow = (qrow0 + qi * 16 + lr) * 1024 + hc;
#pragma unroll
    for (int ct = 0; ct < 4; ++ct) {
      uint2 p;
      p.x = pack_hu(acc_pv[qi][ct][0] * inv, acc_pv[qi][ct][1] * inv);
      p.y = pack_hu(acc_pv[qi][ct][2] * inv, acc_pv[qi][ct][3] * inv);
      *(uint2*)&attout[orow + ct * 16 + lq * 4] = p;
    }
  }
}

extern "C" void kernel_launch(void* const* d_in, const int* in_sizes, int n_in,
                              void* d_out, int out_size, void* d_ws, size_t ws_size,
                              hipStream_t stream) {
  (void)in_sizes; (void)n_in; (void)out_size; (void)ws_size;
  const float* x    = (const float*)d_in[0];
  const float* Wqkv = (const float*)d_in[1];
  const float* Wout = (const float*)d_in[2];
  float* out = (float*)d_out;
  char* ws = (char*)d_ws;

  // workspace layout (80 MB). attout occupies the former xb region (xb gone).
  unsigned short* attout = (unsigned short*)(ws);               // 33,554,432 B
  unsigned short* wqkvb  = (unsigned short*)(ws + 33554432);    //  6,291,456 B
  unsigned short* woutb  = (unsigned short*)(ws + 39845888);    //  2,097,152 B
  unsigned short* qbuf   = (unsigned short*)(ws + 41943040);    // 33,554,432 B
  unsigned short* kbuf   = (unsigned short*)(ws + 75497472);    //  4,194,304 B
  unsigned short* vtb    = (unsigned short*)(ws + 79691776);    //  4,194,304 B

  cvt_kernel<<<3072, 256, 0, stream>>>(Wqkv, wqkvb, 3 * 1024 * 1024);
  cvt_kernel<<<1024, 256, 0, stream>>>(Wout, woutb, 1024 * 1024);

  // Q = (x @ Wq^T) * hd^-0.5  -> qbuf (8-phase 256^2, f32-A fused conversion)
  gemm8p<true, false><<<dim3(64, 4), 512, 0, stream>>>(
      (const void*)x, wqkvb, (void*)qbuf, 0.125f);
  // K,V at dilated rows (every 8th, f32-A): K -> kbuf, V -> vtb (sigma V^T)
  gemm_bt<2><<<dim3(16, 16), 256, 0, stream>>>(
      x, wqkvb + 1024 * 1024, (void*)kbuf, vtb, 1.0f, 8192, 1024, 1024);

  attn_kernel<<<512, 512, 0, stream>>>(qbuf, kbuf, vtb, attout);

  // final projection: out = attout @ Wout^T (f32 output, 8-phase 256^2, bf16 A)
  gemm8p<false, true><<<dim3(64, 4), 512, 0, stream>>>(
      (const void*)attout, woutb, (void*)out, 1.0f);
}

// Round 14
// 170.079 us; speedup vs baseline: 1.0263x; 1.0263x over previous
//
#include <hip/hip_runtime.h>
#include <hip/hip_bf16.h>
#include <stdint.h>

// Problem constants: B=2, M=8192, D=1024, H=16, hd=64, SEG=2048, DIL=8
// => S=4 segments, Kn=256 dilated keys/segment, nb=32 query blocks of 64.

typedef __attribute__((ext_vector_type(8))) short short8;
typedef __attribute__((ext_vector_type(4))) float f32x4;

#define DEVI static __device__ __forceinline__

DEVI unsigned short f2bf(float f) {
  union { float f; uint32_t u; } v; v.f = f;
  return (unsigned short)((v.u + 0x7FFFu + ((v.u >> 16) & 1u)) >> 16);
}

// RNE pair pack (epilogue-quality).
DEVI uint32_t pack_bf16(float lo, float hi) {
  return (uint32_t)f2bf(lo) | ((uint32_t)f2bf(hi) << 16);
}

// Round-half-up pair pack (hot paths): 5 VALU ops vs ~10. Ties-only diff.
DEVI uint32_t pack_hu(float lo, float hi) {
  union { float f; uint32_t u; } a, b; a.f = lo; b.f = hi;
  return ((a.u + 0x8000u) >> 16) | ((b.u + 0x8000u) & 0xFFFF0000u);
}

DEVI void gload_lds16(const void* g, void* l) {
  __builtin_amdgcn_global_load_lds((const __attribute__((address_space(1))) void*)g,
                                   (__attribute__((address_space(3))) void*)l,
                                   16, 0, 0);
}

// ---------------- f32 -> bf16 convert ----------------
__global__ void cvt_kernel(const float* __restrict__ in, unsigned short* __restrict__ out, int n) {
  int i = (blockIdx.x * 256 + threadIdx.x) * 4;
  if (i >= n) return;
  float4 f = *(const float4*)(in + i);
  uint2 o;
  o.x = (uint32_t)f2bf(f.x) | ((uint32_t)f2bf(f.y) << 16);
  o.y = (uint32_t)f2bf(f.z) | ((uint32_t)f2bf(f.w) << 16);
  *(uint2*)(out + i) = o;
}

// ======== 8-phase 256x256 GEMM: r12 schedule (proven best) ========
// 512 threads = 8 waves (2M x 4N); per-wave C 128x64, rows/cols interleaved
// across tile halves; gray-code quadrants. A-frags reload q=0,2 (8 rds),
// B-halves both resident, loaded q=0,1 (4 rds) -> 48 ds_read_b128/iter.
// Rhythm: {ds_read; stage; BAR; lgkm0+schedbar; prio1 MFMA16 prio0; [vmcnt]; BAR}
// Batch stages (4 gloads) at p0,p2,p4,p6; waits vmcnt(4) at p0,p3,p4,p7;
// tail t=7: p4 vmcnt(0). Per-unit retire/overwrite margins verified (r12).
#define STAGE_A(bf, hf, kt) do { \
  gload_lds16(Abase + (long)((hf) * 128 + srow0) * 1024 + (kt) * 64 + scol0, &smA[bf][hf][se0]); \
  gload_lds16(Abase + (long)((hf) * 128 + srow1) * 1024 + (kt) * 64 + scol1, &smA[bf][hf][se1]); \
} while (0)
#define STAGE_B(bf, hf, kt) do { \
  gload_lds16(Bbase + (long)((hf) * 128 + srow0) * 1024 + (kt) * 64 + scol0, &smB[bf][hf][se0]); \
  gload_lds16(Bbase + (long)((hf) * 128 + srow1) * 1024 + (kt) * 64 + scol1, &smB[bf][hf][se1]); \
} while (0)

template<bool OUT_F32>
__global__ __launch_bounds__(512, 1) void gemm8p(
    const unsigned short* __restrict__ A, const unsigned short* __restrict__ B,
    void* __restrict__ Cv, float scale)
{
  __shared__ unsigned short smA[2][2][128 * 64];   // [buf][half][r][k] swizzled
  __shared__ unsigned short smB[2][2][128 * 64];
  const int tid = threadIdx.x;
  const int tm = blockIdx.x, tn = blockIdx.y;
  const int w = tid >> 6, lane = tid & 63;
  const int wm = w >> 2, wn = w & 3;
  const int lr = lane & 15, lq = lane >> 4;

  const int e0 = tid * 8,        e1 = (512 + tid) * 8;
  const int srow0 = e0 >> 6,     srow1 = e1 >> 6;
  const int sc0 = (e0 >> 3) & 7, sc1 = (e1 >> 3) & 7;
  const int scol0 = (sc0 ^ (srow0 & 7)) * 8, scol1 = (sc1 ^ (srow1 & 7)) * 8;
  const int se0 = e0, se1 = e1;

  const unsigned short* Abase = A + (long)tm * 256 * 1024;
  const unsigned short* Bbase = B + (long)tn * 256 * 1024;

  f32x4 acc[8][4] = {};
  short8 af[4][2];        // current A-half fragments (persist 2 phases)
  short8 bfr[2][2][2];    // BOTH B-half fragments [half][nj2][kk]

  // prologue: stage tile 0 into buf0 (A0,B0 first 4 loads; B1,A1 next 4)
  STAGE_A(0, 0, 0); STAGE_B(0, 0, 0); STAGE_B(0, 1, 0); STAGE_A(0, 1, 0);
  asm volatile("s_waitcnt vmcnt(4)" ::: "memory");
  __builtin_amdgcn_s_barrier();
  asm volatile("" ::: "memory");

  for (int t = 0; t < 8; ++t) {
#pragma unroll
    for (int p = 0; p < 8; ++p) {
      const int o = p >> 2;            // LDS buf: 0 for kt=2t, 1 for kt=2t+1
      const int q = p & 3;
      const int a = (p >> 1) & 1;      // A-half: 0,0,1,1
      const int b = a ^ (q & 1);       // B-half: 0,1,1,0 (gray)

      // ---- ds_read only NEW fragments for this phase
      if (q == 0 || q == 2) {          // new A-half (8 x b128)
#pragma unroll
        for (int mi2 = 0; mi2 < 4; ++mi2) {
          int r = wm * 64 + mi2 * 16 + lr;
#pragma unroll
          for (int kk = 0; kk < 2; ++kk) {
            int kc = kk * 4 + lq;
            af[mi2][kk] = *(const short8*)&smA[o][a][r * 64 + ((kc ^ (r & 7)) * 8)];
          }
        }
      }
      if (q == 0 || q == 1) {          // new B-half b (4 x b128), kept resident
#pragma unroll
        for (int nj2 = 0; nj2 < 2; ++nj2) {
          int r = wn * 32 + nj2 * 16 + lr;
#pragma unroll
          for (int kk = 0; kk < 2; ++kk) {
            int kc = kk * 4 + lq;
            bfr[b][nj2][kk] = *(const short8*)&smB[o][b][r * 64 + ((kc ^ (r & 7)) * 8)];
          }
        }
      }

      // ---- batch stage (2 units = 4 gloads) at p0,p2,p4,p6
      switch (p) {
        case 0: STAGE_A(1, 0, 2 * t + 1); STAGE_B(1, 0, 2 * t + 1); break;
        case 2: STAGE_B(1, 1, 2 * t + 1); STAGE_A(1, 1, 2 * t + 1); break;
        case 4: if (t < 7) { STAGE_A(0, 0, 2 * t + 2); STAGE_B(0, 0, 2 * t + 2); } break;
        case 6: if (t < 7) { STAGE_B(0, 1, 2 * t + 2); STAGE_A(0, 1, 2 * t + 2); } break;
      }

      // ---- first barrier; drain ds_reads; MFMA
      __builtin_amdgcn_s_barrier();
      if (q != 3) {
        asm volatile("s_waitcnt lgkmcnt(0)" ::: "memory");
        __builtin_amdgcn_sched_barrier(0);
      }

      __builtin_amdgcn_s_setprio(1);
#pragma unroll
      for (int kk = 0; kk < 2; ++kk)
#pragma unroll
        for (int mi2 = 0; mi2 < 4; ++mi2)
#pragma unroll
          for (int nj2 = 0; nj2 < 2; ++nj2)
            acc[a * 4 + mi2][b * 2 + nj2] = __builtin_amdgcn_mfma_f32_16x16x32_bf16(
                af[mi2][kk], bfr[b][nj2][kk], acc[a * 4 + mi2][b * 2 + nj2], 0, 0, 0);
      __builtin_amdgcn_s_setprio(0);

      // ---- counted wait (p0,p3,p4,p7) + second barrier
      if (t < 7) {
        if (p == 0 || p == 3 || p == 4 || p == 7)
          asm volatile("s_waitcnt vmcnt(4)" ::: "memory");
      } else {
        if (p == 0 || p == 3)  asm volatile("s_waitcnt vmcnt(4)" ::: "memory");
        else if (p == 4)       asm volatile("s_waitcnt vmcnt(0)" ::: "memory");
      }
      __builtin_amdgcn_s_barrier();
      asm volatile("" ::: "memory");
    }
  }

  // ---- epilogue
  const int row0 = tm * 256 + wm * 64 + lq * 4;
  const int col0 = tn * 256 + wn * 32 + lr;
#pragma unroll
  for (int mi = 0; mi < 8; ++mi) {
    int row = row0 + (mi & 3) * 16 + (mi >> 2) * 128;
#pragma unroll
    for (int nj = 0; nj < 4; ++nj) {
      int col = col0 + (nj & 1) * 16 + (nj >> 1) * 128;
#pragma unroll
      for (int rr = 0; rr < 4; ++rr) {
        float v = acc[mi][nj][rr] * scale;
        long off = (long)(row + rr) * 1024 + col;
        if (OUT_F32) ((float*)Cv)[off] = v;
        else         ((unsigned short*)Cv)[off] = f2bf(v);
      }
    }
  }
}

// ---------------- 128^2 GEMM for the KV split (bf16 A from xb) ----------------
// EPI 2: tn<8 -> bf16 K rows to Cv; tn>=8 -> V TRANSPOSED + sigma-permuted to
// Cv2 (row = seg*1024+f; u32 col c packs tokens (32*(c>>4)+(c&15), +16)).
template<int EPI>
__global__ __launch_bounds__(256, 2) void gemm_bt(
    const unsigned short* __restrict__ A, const unsigned short* __restrict__ B,
    void* __restrict__ Cv, unsigned short* __restrict__ Cv2,
    float scale, long a_row_stride, int ldc, int K)
{
  __shared__ unsigned short smA[128 * 64];
  __shared__ unsigned short smB[128 * 64];
  const int tid = threadIdx.x;
  const int tm = blockIdx.x, tn = blockIdx.y;
  const int w = tid >> 6, lane = tid & 63;
  const int wr = (w >> 1) * 64, wc = (w & 1) * 64;
  const int lr = lane & 15, lq = lane >> 4;

  int se[4], srow[4], scol[4];
#pragma unroll
  for (int i = 0; i < 4; ++i) {
    int e = (i * 256 + tid) * 8;
    int r = e >> 6;
    int cc = (e >> 3) & 7;
    se[i] = e; srow[i] = r; scol[i] = (cc ^ (r & 7)) * 8;
  }

  f32x4 acc[4][4] = {};

  for (int kt = 0; kt < K / 64; ++kt) {
    if (kt) __syncthreads();
#pragma unroll
    for (int i = 0; i < 4; ++i)
      gload_lds16(A + (long)(tm * 128 + srow[i]) * a_row_stride + kt * 64 + scol[i], &smA[se[i]]);
#pragma unroll
    for (int i = 0; i < 4; ++i)
      gload_lds16(B + (long)(tn * 128 + srow[i]) * K + kt * 64 + scol[i], &smB[se[i]]);
    __syncthreads();

#pragma unroll
    for (int kk = 0; kk < 2; ++kk) {
      int kc = kk * 4 + lq;
      short8 af[4], bfm[4];
#pragma unroll
      for (int i = 0; i < 4; ++i) {
        int row = wr + i * 16 + lr;
        af[i] = *(const short8*)&smA[row * 64 + ((kc ^ (row & 7)) * 8)];
      }
#pragma unroll
      for (int j = 0; j < 4; ++j) {
        int row = wc + j * 16 + lr;
        bfm[j] = *(const short8*)&smB[row * 64 + ((kc ^ (row & 7)) * 8)];
      }
#pragma unroll
      for (int i = 0; i < 4; ++i)
#pragma unroll
        for (int j = 0; j < 4; ++j)
          acc[i][j] = __builtin_amdgcn_mfma_f32_16x16x32_bf16(af[i], bfm[j], acc[i][j], 0, 0, 0);
    }
  }

  if (EPI == 2 && tn >= 8) {
    const int fbase = (tn - 8) * 128 + wc;
#pragma unroll
    for (int ip = 0; ip < 4; ip += 2) {
      int t0 = tm * 128 + wr + ip * 16 + lq * 4;
      int seg = t0 >> 8;
      int ts  = t0 & 255;
      int c32 = (ts >> 5) * 16 + (ts & 15);
#pragma unroll
      for (int j = 0; j < 4; ++j) {
        int f = fbase + j * 16 + lr;
        uint32_t* rp = (uint32_t*)&Cv2[((long)(seg * 1024 + f)) * 256];
        uint4 U;
        U.x = pack_bf16(acc[ip][j][0] * scale, acc[ip + 1][j][0] * scale);
        U.y = pack_bf16(acc[ip][j][1] * scale, acc[ip + 1][j][1] * scale);
        U.z = pack_bf16(acc[ip][j][2] * scale, acc[ip + 1][j][2] * scale);
        U.w = pack_bf16(acc[ip][j][3] * scale, acc[ip + 1][j][3] * scale);
        *(uint4*)&rp[c32] = U;
      }
    }
    return;
  }

#pragma unroll
  for (int i = 0; i < 4; ++i) {
    int rg0 = tm * 128 + wr + i * 16 + lq * 4;
#pragma unroll
    for (int j = 0; j < 4; ++j) {
      int cg = tn * 128 + wc + j * 16 + lr;
#pragma unroll
      for (int r = 0; r < 4; ++r) {
        float v = acc[i][j][r] * scale;
        long off = (long)(rg0 + r) * ldc + cg;
        if (EPI == 0) ((float*)Cv)[off] = v;
        else          ((unsigned short*)Cv)[off] = f2bf(v);
      }
    }
  }
}

// ---------------- segment-local dilated attention, 2-deep pipeline ----------
// 512-thread blocks, 8 independent waves. NO LDS V-staging (per-head V^T slice
// is 32 KB, shared by 4 blocks -> L2-hot; guide common-mistake #7): PV frags
// read directly from global, issued BEFORE the max/exp chain so L2 latency
// hides under softmax VALU. Zero barriers. Tree-shaped column max (depth ~4
// vs 16 serial). Round-half-up packs. w32 stride 20 (conflict-free).
__global__ __launch_bounds__(512, 2) void attn_kernel(
    const unsigned short* __restrict__ qb,    // [16384][1024] bf16, q*scale
    const unsigned short* __restrict__ kb,    // [2048][1024] bf16 dilated keys
    const unsigned short* __restrict__ vtb,   // sigma-permuted V^T
    unsigned short* __restrict__ attout)      // [16384][1024] bf16, col = h*64+d
{
  __shared__ uint32_t w32[8][64][20];         // per-wave [q][col] slices, 40 KB

  const int u = (blockIdx.x & 7) * 64 + (blockIdx.x >> 3);
  const int quarter = u & 3, h = (u >> 2) & 15, s = (u >> 6) & 3, b = u >> 8;
  const int tid = threadIdx.x, w = tid >> 6, lane = tid & 63;
  const int lr = lane & 15, lq = lane >> 4;
  const long qrow0 = (long)b * 8192 + s * 2048 + quarter * 512 + w * 64;
  const int hc = h * 64;

  const unsigned short* kbase = kb + ((long)(b * 4 + s) * 256) * 1024 + hc;
  const unsigned short* vbase = vtb + ((long)(b * 4 + s) * 1024 + hc) * 256;

  const unsigned short* qbase = qb + qrow0 * 1024 + hc;
  short8 aq[4][2];
#pragma unroll
  for (int i = 0; i < 4; ++i)
#pragma unroll
    for (int kk = 0; kk < 2; ++kk)
      aq[i][kk] = *(const short8*)&qbase[(i * 16 + lr) * 1024 + (kk * 4 + lq) * 8];

  short8 ones;
#pragma unroll
  for (int e = 0; e < 8; ++e) ones[e] = (short)0x3F80;  // bf16 1.0

  uint32_t (*wsl)[20] = w32[w];

  f32x4 acc_pv[4][4] = {};
  f32x4 acc_den[4] = {};
  short8 bk0[2][2], bk1[2][2];
  f32x4 sA[4][2], sB[4][2];

#define LOADK(BK, CC) do { \
  _Pragma("unroll") for (int j = 0; j < 2; ++j) \
    _Pragma("unroll") for (int kk = 0; kk < 2; ++kk) \
      BK[j][kk] = *(const short8*)&kbase[(long)((CC) * 32 + j * 16 + lr) * 1024 + (kk * 4 + lq) * 8]; \
} while (0)

#define QKT(S, BK) do { \
  _Pragma("unroll") for (int i = 0; i < 4; ++i) \
    _Pragma("unroll") for (int j = 0; j < 2; ++j) { \
      f32x4 z = {0.f, 0.f, 0.f, 0.f}; S[i][j] = z; } \
  _Pragma("unroll") for (int kk = 0; kk < 2; ++kk) \
    _Pragma("unroll") for (int i = 0; i < 4; ++i) \
      _Pragma("unroll") for (int j = 0; j < 2; ++j) \
        S[i][j] = __builtin_amdgcn_mfma_f32_16x16x32_bf16(aq[i][kk], BK[j][kk], S[i][j], 0, 0, 0); \
} while (0)

#define SOFTPV(S, CC) do { \
  /* issue V^T fragment loads FIRST: latency hides under max/exp VALU */ \
  short8 av_[4]; \
  _Pragma("unroll") for (int ct = 0; ct < 4; ++ct) \
    av_[ct] = *(const short8*)&vbase[(ct * 16 + lr) * 256 + ((CC) * 4 + lq) * 8]; \
  /* tree max per key column (depth ~4) */ \
  float p0[4], p1[4]; \
  _Pragma("unroll") for (int i = 0; i < 4; ++i) { \
    p0[i] = fmaxf(fmaxf(S[i][0][0], S[i][0][1]), fmaxf(S[i][0][2], S[i][0][3])); \
    p1[i] = fmaxf(fmaxf(S[i][1][0], S[i][1][1]), fmaxf(S[i][1][2], S[i][1][3])); \
  } \
  float c0 = fmaxf(fmaxf(p0[0], p0[1]), fmaxf(p0[2], p0[3])); \
  float c1 = fmaxf(fmaxf(p1[0], p1[1]), fmaxf(p1[2], p1[3])); \
  c0 = fmaxf(c0, __shfl_xor(c0, 16)); c0 = fmaxf(c0, __shfl_xor(c0, 32)); \
  c1 = fmaxf(c1, __shfl_xor(c1, 16)); c1 = fmaxf(c1, __shfl_xor(c1, 32)); \
  _Pragma("unroll") for (int i = 0; i < 4; ++i) \
    _Pragma("unroll") for (int r = 0; r < 4; ++r) { \
      int qq = i * 16 + lq * 4 + r; \
      wsl[qq][lr] = pack_hu(__expf(S[i][0][r] - c0), __expf(S[i][1][r] - c1)); } \
  _Pragma("unroll") for (int qi = 0; qi < 4; ++qi) { \
    short8 bw = *(const short8*)&wsl[qi * 16 + lr][lq * 4]; \
    acc_den[qi] = __builtin_amdgcn_mfma_f32_16x16x32_bf16(ones, bw, acc_den[qi], 0, 0, 0); \
    _Pragma("unroll") for (int ct = 0; ct < 4; ++ct) \
      acc_pv[qi][ct] = __builtin_amdgcn_mfma_f32_16x16x32_bf16(av_[ct], bw, acc_pv[qi][ct], 0, 0, 0); } \
} while (0)

  // prologue: K chunks 0,1 in regs; scores for chunk 0
  LOADK(bk0, 0);
  LOADK(bk1, 1);
  QKT(sA, bk0);

  // 2-deep pipeline, unrolled (named banks; no runtime indexing)
  LOADK(bk0, 2); QKT(sB, bk1); SOFTPV(sA, 0);
  LOADK(bk1, 3); QKT(sA, bk0); SOFTPV(sB, 1);
  LOADK(bk0, 4); QKT(sB, bk1); SOFTPV(sA, 2);
  LOADK(bk1, 5); QKT(sA, bk0); SOFTPV(sB, 3);
  LOADK(bk0, 6); QKT(sB, bk1); SOFTPV(sA, 4);
  LOADK(bk1, 7); QKT(sA, bk0); SOFTPV(sB, 5);
                 QKT(sB, bk1); SOFTPV(sA, 6);
                               SOFTPV(sB, 7);

  // ---- epilogue: out[q][f] = num/den, packed 8B stores
#pragma unroll
  for (int qi = 0; qi < 4; ++qi) {
    float inv = 1.0f / (acc_den[qi][0] + 1e-10f);
    long orow = (qrow0 + qi * 16 + lr) * 1024 + hc;
#pragma unroll
    for (int ct = 0; ct < 4; ++ct) {
      uint2 p;
      p.x = pack_hu(acc_pv[qi][ct][0] * inv, acc_pv[qi][ct][1] * inv);
      p.y = pack_hu(acc_pv[qi][ct][2] * inv, acc_pv[qi][ct][3] * inv);
      *(uint2*)&attout[orow + ct * 16 + lq * 4] = p;
    }
  }
}

extern "C" void kernel_launch(void* const* d_in, const int* in_sizes, int n_in,
                              void* d_out, int out_size, void* d_ws, size_t ws_size,
                              hipStream_t stream) {
  (void)in_sizes; (void)n_in; (void)out_size; (void)ws_size;
  const float* x    = (const float*)d_in[0];
  const float* Wqkv = (const float*)d_in[1];
  const float* Wout = (const float*)d_in[2];
  float* out = (float*)d_out;
  char* ws = (char*)d_ws;

  // workspace layout (80 MB). xb aliases attout: xb is dead before attn writes.
  unsigned short* xb     = (unsigned short*)(ws);               // 33,554,432 B
  unsigned short* attout = (unsigned short*)(ws);               // (same region)
  unsigned short* wqkvb  = (unsigned short*)(ws + 33554432);    //  6,291,456 B
  unsigned short* woutb  = (unsigned short*)(ws + 39845888);    //  2,097,152 B
  unsigned short* qbuf   = (unsigned short*)(ws + 41943040);    // 33,554,432 B
  unsigned short* kbuf   = (unsigned short*)(ws + 75497472);    //  4,194,304 B
  unsigned short* vtb    = (unsigned short*)(ws + 79691776);    //  4,194,304 B

  cvt_kernel<<<16384, 256, 0, stream>>>(x, xb, 16777216);
  cvt_kernel<<<3072, 256, 0, stream>>>(Wqkv, wqkvb, 3 * 1024 * 1024);
  cvt_kernel<<<1024, 256, 0, stream>>>(Wout, woutb, 1024 * 1024);

  // Q = (x @ Wq^T) * hd^-0.5  -> qbuf (8-phase 256^2)
  gemm8p<false><<<dim3(64, 4), 512, 0, stream>>>(xb, wqkvb, (void*)qbuf, 0.125f);
  // K,V at dilated rows (every 8th): K -> kbuf [2048][1024], V -> vtb (sigma V^T)
  gemm_bt<2><<<dim3(16, 16), 256, 0, stream>>>(
      xb, wqkvb + 1024 * 1024, (void*)kbuf, vtb, 1.0f, 8192, 1024, 1024);

  attn_kernel<<<512, 512, 0, stream>>>(qbuf, kbuf, vtb, attout);

  // final projection: out = attout @ Wout^T (f32 output, 8-phase 256^2)
  gemm8p<true><<<dim3(64, 4), 512, 0, stream>>>(attout, woutb, (void*)out, 1.0f);
}

// Round 15
// 167.915 us; speedup vs baseline: 1.0395x; 1.0129x over previous
//
#include <hip/hip_runtime.h>
#include <hip/hip_bf16.h>
#include <stdint.h>

// Problem constants: B=2, M=8192, D=1024, H=16, hd=64, SEG=2048, DIL=8
// => S=4 segments, Kn=256 dilated keys/segment, nb=32 query blocks of 64.

typedef __attribute__((ext_vector_type(8))) short short8;
typedef __attribute__((ext_vector_type(4))) float f32x4;

#define DEVI static __device__ __forceinline__

DEVI unsigned short f2bf(float f) {
  union { float f; uint32_t u; } v; v.f = f;
  return (unsigned short)((v.u + 0x7FFFu + ((v.u >> 16) & 1u)) >> 16);
}

// RNE pair pack (epilogue-quality).
DEVI uint32_t pack_bf16(float lo, float hi) {
  return (uint32_t)f2bf(lo) | ((uint32_t)f2bf(hi) << 16);
}

// Round-half-up pair pack (hot paths): 5 VALU ops vs ~10. Ties-only diff.
DEVI uint32_t pack_hu(float lo, float hi) {
  union { float f; uint32_t u; } a, b; a.f = lo; b.f = hi;
  return ((a.u + 0x8000u) >> 16) | ((b.u + 0x8000u) & 0xFFFF0000u);
}

DEVI void gload_lds16(const void* g, void* l) {
  __builtin_amdgcn_global_load_lds((const __attribute__((address_space(1))) void*)g,
                                   (__attribute__((address_space(3))) void*)l,
                                   16, 0, 0);
}

// ---------------- f32 -> bf16 convert ----------------
__global__ void cvt_kernel(const float* __restrict__ in, unsigned short* __restrict__ out, int n) {
  int i = (blockIdx.x * 256 + threadIdx.x) * 4;
  if (i >= n) return;
  float4 f = *(const float4*)(in + i);
  uint2 o;
  o.x = (uint32_t)f2bf(f.x) | ((uint32_t)f2bf(f.y) << 16);
  o.y = (uint32_t)f2bf(f.z) | ((uint32_t)f2bf(f.w) << 16);
  *(uint2*)(out + i) = o;
}

// ======== 8-phase 256x256 GEMM: r12 schedule (proven best) ========
// 512 threads = 8 waves (2M x 4N); per-wave C 128x64, rows/cols interleaved
// across tile halves; gray-code quadrants. A-frags reload q=0,2 (8 rds),
// B-halves both resident, loaded q=0,1 (4 rds) -> 48 ds_read_b128/iter.
// Rhythm: {ds_read; stage; BAR; lgkm0+schedbar; prio1 MFMA16 prio0; [vmcnt]; BAR}
// Batch stages (4 gloads) at p0,p2,p4,p6; waits vmcnt(4) at p0,p3,p4,p7;
// tail t=7: p4 vmcnt(0). Per-unit retire/overwrite margins verified (r12).
// OUT_F32 epilogue: per-wave LDS transpose (stride-33 f32, wave-private, no
// barriers) -> 2x float4 stores/thread/pass; 4-lane groups = full 128B lines
// (fixes the measured 67 MB vs 32 MB write amplification of the scatter).
#define STAGE_A(bf, hf, kt) do { \
  gload_lds16(Abase + (long)((hf) * 128 + srow0) * 1024 + (kt) * 64 + scol0, &smA[bf][hf][se0]); \
  gload_lds16(Abase + (long)((hf) * 128 + srow1) * 1024 + (kt) * 64 + scol1, &smA[bf][hf][se1]); \
} while (0)
#define STAGE_B(bf, hf, kt) do { \
  gload_lds16(Bbase + (long)((hf) * 128 + srow0) * 1024 + (kt) * 64 + scol0, &smB[bf][hf][se0]); \
  gload_lds16(Bbase + (long)((hf) * 128 + srow1) * 1024 + (kt) * 64 + scol1, &smB[bf][hf][se1]); \
} while (0)

template<bool OUT_F32>
__global__ __launch_bounds__(512, 1) void gemm8p(
    const unsigned short* __restrict__ A, const unsigned short* __restrict__ B,
    void* __restrict__ Cv, float scale)
{
  __shared__ unsigned short smA[2][2][128 * 64];   // [buf][half][r][k] swizzled
  __shared__ unsigned short smB[2][2][128 * 64];
  const int tid = threadIdx.x;
  const int tm = blockIdx.x, tn = blockIdx.y;
  const int w = tid >> 6, lane = tid & 63;
  const int wm = w >> 2, wn = w & 3;
  const int lr = lane & 15, lq = lane >> 4;

  const int e0 = tid * 8,        e1 = (512 + tid) * 8;
  const int srow0 = e0 >> 6,     srow1 = e1 >> 6;
  const int sc0 = (e0 >> 3) & 7, sc1 = (e1 >> 3) & 7;
  const int scol0 = (sc0 ^ (srow0 & 7)) * 8, scol1 = (sc1 ^ (srow1 & 7)) * 8;
  const int se0 = e0, se1 = e1;

  const unsigned short* Abase = A + (long)tm * 256 * 1024;
  const unsigned short* Bbase = B + (long)tn * 256 * 1024;

  f32x4 acc[8][4] = {};
  short8 af[4][2];        // current A-half fragments (persist 2 phases)
  short8 bfr[2][2][2];    // BOTH B-half fragments [half][nj2][kk]

  // prologue: stage tile 0 into buf0 (A0,B0 first 4 loads; B1,A1 next 4)
  STAGE_A(0, 0, 0); STAGE_B(0, 0, 0); STAGE_B(0, 1, 0); STAGE_A(0, 1, 0);
  asm volatile("s_waitcnt vmcnt(4)" ::: "memory");
  __builtin_amdgcn_s_barrier();
  asm volatile("" ::: "memory");

  for (int t = 0; t < 8; ++t) {
#pragma unroll
    for (int p = 0; p < 8; ++p) {
      const int o = p >> 2;            // LDS buf: 0 for kt=2t, 1 for kt=2t+1
      const int q = p & 3;
      const int a = (p >> 1) & 1;      // A-half: 0,0,1,1
      const int b = a ^ (q & 1);       // B-half: 0,1,1,0 (gray)

      // ---- ds_read only NEW fragments for this phase
      if (q == 0 || q == 2) {          // new A-half (8 x b128)
#pragma unroll
        for (int mi2 = 0; mi2 < 4; ++mi2) {
          int r = wm * 64 + mi2 * 16 + lr;
#pragma unroll
          for (int kk = 0; kk < 2; ++kk) {
            int kc = kk * 4 + lq;
            af[mi2][kk] = *(const short8*)&smA[o][a][r * 64 + ((kc ^ (r & 7)) * 8)];
          }
        }
      }
      if (q == 0 || q == 1) {          // new B-half b (4 x b128), kept resident
#pragma unroll
        for (int nj2 = 0; nj2 < 2; ++nj2) {
          int r = wn * 32 + nj2 * 16 + lr;
#pragma unroll
          for (int kk = 0; kk < 2; ++kk) {
            int kc = kk * 4 + lq;
            bfr[b][nj2][kk] = *(const short8*)&smB[o][b][r * 64 + ((kc ^ (r & 7)) * 8)];
          }
        }
      }

      // ---- batch stage (2 units = 4 gloads) at p0,p2,p4,p6
      switch (p) {
        case 0: STAGE_A(1, 0, 2 * t + 1); STAGE_B(1, 0, 2 * t + 1); break;
        case 2: STAGE_B(1, 1, 2 * t + 1); STAGE_A(1, 1, 2 * t + 1); break;
        case 4: if (t < 7) { STAGE_A(0, 0, 2 * t + 2); STAGE_B(0, 0, 2 * t + 2); } break;
        case 6: if (t < 7) { STAGE_B(0, 1, 2 * t + 2); STAGE_A(0, 1, 2 * t + 2); } break;
      }

      // ---- first barrier; drain ds_reads; MFMA
      __builtin_amdgcn_s_barrier();
      if (q != 3) {
        asm volatile("s_waitcnt lgkmcnt(0)" ::: "memory");
        __builtin_amdgcn_sched_barrier(0);
      }

      __builtin_amdgcn_s_setprio(1);
#pragma unroll
      for (int kk = 0; kk < 2; ++kk)
#pragma unroll
        for (int mi2 = 0; mi2 < 4; ++mi2)
#pragma unroll
          for (int nj2 = 0; nj2 < 2; ++nj2)
            acc[a * 4 + mi2][b * 2 + nj2] = __builtin_amdgcn_mfma_f32_16x16x32_bf16(
                af[mi2][kk], bfr[b][nj2][kk], acc[a * 4 + mi2][b * 2 + nj2], 0, 0, 0);
      __builtin_amdgcn_s_setprio(0);

      // ---- counted wait (p0,p3,p4,p7) + second barrier
      if (t < 7) {
        if (p == 0 || p == 3 || p == 4 || p == 7)
          asm volatile("s_waitcnt vmcnt(4)" ::: "memory");
      } else {
        if (p == 0 || p == 3)  asm volatile("s_waitcnt vmcnt(4)" ::: "memory");
        else if (p == 4)       asm volatile("s_waitcnt vmcnt(0)" ::: "memory");
      }
      __builtin_amdgcn_s_barrier();
      asm volatile("" ::: "memory");
    }
  }

  // ---- epilogue
  if (OUT_F32) {
    // per-wave LDS transpose -> coalesced float4 stores (full 128B lines).
    float* scratch = (float*)&smA[0][0][0] + w * 544;   // 16*33=528 f32/wave
    float* Cf = (float*)Cv;
#pragma unroll
    for (int ai = 0; ai < 8; ++ai) {
#pragma unroll
      for (int b2 = 0; b2 < 2; ++b2) {
        // write 16x32 subtile (stride 33: banks <=2-way)
#pragma unroll
        for (int nj2 = 0; nj2 < 2; ++nj2)
#pragma unroll
          for (int rr = 0; rr < 4; ++rr)
            scratch[(lq * 4 + rr) * 33 + nj2 * 16 + lr] = acc[ai][b2 * 2 + nj2][rr] * scale;
        asm volatile("s_waitcnt lgkmcnt(0)" ::: "memory");
        __builtin_amdgcn_sched_barrier(0);
        // read row-major: lane -> row lane>>2, 8 cols at (lane&3)*8
        int rr2 = lane >> 2, cb = (lane & 3) * 8;
        float4 v0, v1;
        v0.x = scratch[rr2 * 33 + cb + 0]; v0.y = scratch[rr2 * 33 + cb + 1];
        v0.z = scratch[rr2 * 33 + cb + 2]; v0.w = scratch[rr2 * 33 + cb + 3];
        v1.x = scratch[rr2 * 33 + cb + 4]; v1.y = scratch[rr2 * 33 + cb + 5];
        v1.z = scratch[rr2 * 33 + cb + 6]; v1.w = scratch[rr2 * 33 + cb + 7];
        asm volatile("s_waitcnt lgkmcnt(0)" ::: "memory");
        __builtin_amdgcn_sched_barrier(0);
        long rowg = tm * 256 + wm * 64 + (ai & 3) * 16 + (ai >> 2) * 128 + rr2;
        long colg = tn * 256 + wn * 32 + b2 * 128 + cb;
        *(float4*)&Cf[rowg * 1024 + colg] = v0;
        *(float4*)&Cf[rowg * 1024 + colg + 4] = v1;
      }
    }
  } else {
    const int row0 = tm * 256 + wm * 64 + lq * 4;
    const int col0 = tn * 256 + wn * 32 + lr;
#pragma unroll
    for (int mi = 0; mi < 8; ++mi) {
      int row = row0 + (mi & 3) * 16 + (mi >> 2) * 128;
#pragma unroll
      for (int nj = 0; nj < 4; ++nj) {
        int col = col0 + (nj & 1) * 16 + (nj >> 1) * 128;
#pragma unroll
        for (int rr = 0; rr < 4; ++rr)
          ((unsigned short*)Cv)[(long)(row + rr) * 1024 + col] = f2bf(acc[mi][nj][rr] * scale);
      }
    }
  }
}

// ---------------- 128^2 GEMM for the KV split (bf16 A from xb) ----------------
// EPI 2: tn<8 -> bf16 K rows to Cv; tn>=8 -> V TRANSPOSED + sigma-permuted to
// Cv2 (row = seg*1024+f; u32 col c packs tokens (32*(c>>4)+(c&15), +16)).
template<int EPI>
__global__ __launch_bounds__(256, 2) void gemm_bt(
    const unsigned short* __restrict__ A, const unsigned short* __restrict__ B,
    void* __restrict__ Cv, unsigned short* __restrict__ Cv2,
    float scale, long a_row_stride, int ldc, int K)
{
  __shared__ unsigned short smA[128 * 64];
  __shared__ unsigned short smB[128 * 64];
  const int tid = threadIdx.x;
  const int tm = blockIdx.x, tn = blockIdx.y;
  const int w = tid >> 6, lane = tid & 63;
  const int wr = (w >> 1) * 64, wc = (w & 1) * 64;
  const int lr = lane & 15, lq = lane >> 4;

  int se[4], srow[4], scol[4];
#pragma unroll
  for (int i = 0; i < 4; ++i) {
    int e = (i * 256 + tid) * 8;
    int r = e >> 6;
    int cc = (e >> 3) & 7;
    se[i] = e; srow[i] = r; scol[i] = (cc ^ (r & 7)) * 8;
  }

  f32x4 acc[4][4] = {};

  for (int kt = 0; kt < K / 64; ++kt) {
    if (kt) __syncthreads();
#pragma unroll
    for (int i = 0; i < 4; ++i)
      gload_lds16(A + (long)(tm * 128 + srow[i]) * a_row_stride + kt * 64 + scol[i], &smA[se[i]]);
#pragma unroll
    for (int i = 0; i < 4; ++i)
      gload_lds16(B + (long)(tn * 128 + srow[i]) * K + kt * 64 + scol[i], &smB[se[i]]);
    __syncthreads();

#pragma unroll
    for (int kk = 0; kk < 2; ++kk) {
      int kc = kk * 4 + lq;
      short8 af[4], bfm[4];
#pragma unroll
      for (int i = 0; i < 4; ++i) {
        int row = wr + i * 16 + lr;
        af[i] = *(const short8*)&smA[row * 64 + ((kc ^ (row & 7)) * 8)];
      }
#pragma unroll
      for (int j = 0; j < 4; ++j) {
        int row = wc + j * 16 + lr;
        bfm[j] = *(const short8*)&smB[row * 64 + ((kc ^ (row & 7)) * 8)];
      }
#pragma unroll
      for (int i = 0; i < 4; ++i)
#pragma unroll
        for (int j = 0; j < 4; ++j)
          acc[i][j] = __builtin_amdgcn_mfma_f32_16x16x32_bf16(af[i], bfm[j], acc[i][j], 0, 0, 0);
    }
  }

  if (EPI == 2 && tn >= 8) {
    const int fbase = (tn - 8) * 128 + wc;
#pragma unroll
    for (int ip = 0; ip < 4; ip += 2) {
      int t0 = tm * 128 + wr + ip * 16 + lq * 4;
      int seg = t0 >> 8;
      int ts  = t0 & 255;
      int c32 = (ts >> 5) * 16 + (ts & 15);
#pragma unroll
      for (int j = 0; j < 4; ++j) {
        int f = fbase + j * 16 + lr;
        uint32_t* rp = (uint32_t*)&Cv2[((long)(seg * 1024 + f)) * 256];
        uint4 U;
        U.x = pack_bf16(acc[ip][j][0] * scale, acc[ip + 1][j][0] * scale);
        U.y = pack_bf16(acc[ip][j][1] * scale, acc[ip + 1][j][1] * scale);
        U.z = pack_bf16(acc[ip][j][2] * scale, acc[ip + 1][j][2] * scale);
        U.w = pack_bf16(acc[ip][j][3] * scale, acc[ip + 1][j][3] * scale);
        *(uint4*)&rp[c32] = U;
      }
    }
    return;
  }

#pragma unroll
  for (int i = 0; i < 4; ++i) {
    int rg0 = tm * 128 + wr + i * 16 + lq * 4;
#pragma unroll
    for (int j = 0; j < 4; ++j) {
      int cg = tn * 128 + wc + j * 16 + lr;
#pragma unroll
      for (int r = 0; r < 4; ++r) {
        float v = acc[i][j][r] * scale;
        long off = (long)(rg0 + r) * ldc + cg;
        if (EPI == 0) ((float*)Cv)[off] = v;
        else          ((unsigned short*)Cv)[off] = f2bf(v);
      }
    }
  }
}

// ---------------- segment-local dilated attention, 2-deep pipeline ----------
// r12 structure restored: 512-thread blocks, 8 independent waves, V^T staged
// in LDS once (1 barrier), 2-deep software pipeline with named banks, w32
// stride 20 (conflict-free). Kept from r14: tree max (depth ~4), pack_hu,
// uint2 epilogue stores.
__global__ __launch_bounds__(512, 2) void attn_kernel(
    const unsigned short* __restrict__ qb,    // [16384][1024] bf16, q*scale
    const unsigned short* __restrict__ kb,    // [2048][1024] bf16 dilated keys
    const unsigned short* __restrict__ vtb,   // sigma-permuted V^T
    unsigned short* __restrict__ attout)      // [16384][1024] bf16, col = h*64+d
{
  __shared__ unsigned short v_t[64 * 256];    // [f][g] swizzled, 32 KB
  __shared__ uint32_t w32[8][64][20];         // per-wave [q][col] slices, 40 KB

  const int u = (blockIdx.x & 7) * 64 + (blockIdx.x >> 3);
  const int quarter = u & 3, h = (u >> 2) & 15, s = (u >> 6) & 3, b = u >> 8;
  const int tid = threadIdx.x, w = tid >> 6, lane = tid & 63;
  const int lr = lane & 15, lq = lane >> 4;
  const long qrow0 = (long)b * 8192 + s * 2048 + quarter * 512 + w * 64;
  const int hc = h * 64;

  const unsigned short* kbase = kb + ((long)(b * 4 + s) * 256) * 1024 + hc;
  const unsigned short* vbase = vtb + ((long)(b * 4 + s) * 1024 + hc) * 256;

#pragma unroll
  for (int it = 0; it < 4; ++it) {
    int e = (it * 512 + tid) * 8;
    int f = e >> 8;
    int ch = (e >> 3) & 31;
    gload_lds16(vbase + (long)f * 256 + ((ch ^ (f & 7)) * 8), &v_t[e]);
  }

  const unsigned short* qbase = qb + qrow0 * 1024 + hc;
  short8 aq[4][2];
#pragma unroll
  for (int i = 0; i < 4; ++i)
#pragma unroll
    for (int kk = 0; kk < 2; ++kk)
      aq[i][kk] = *(const short8*)&qbase[(i * 16 + lr) * 1024 + (kk * 4 + lq) * 8];

  __syncthreads();   // V staged (only barrier in the kernel)

  short8 ones;
#pragma unroll
  for (int e = 0; e < 8; ++e) ones[e] = (short)0x3F80;  // bf16 1.0

  uint32_t (*wsl)[20] = w32[w];

  f32x4 acc_pv[4][4] = {};
  f32x4 acc_den[4] = {};
  short8 bk0[2][2], bk1[2][2];
  f32x4 sA[4][2], sB[4][2];

#define LOADK(BK, CC) do { \
  _Pragma("unroll") for (int j = 0; j < 2; ++j) \
    _Pragma("unroll") for (int kk = 0; kk < 2; ++kk) \
      BK[j][kk] = *(const short8*)&kbase[(long)((CC) * 32 + j * 16 + lr) * 1024 + (kk * 4 + lq) * 8]; \
} while (0)

#define QKT(S, BK) do { \
  _Pragma("unroll") for (int i = 0; i < 4; ++i) \
    _Pragma("unroll") for (int j = 0; j < 2; ++j) { \
      f32x4 z = {0.f, 0.f, 0.f, 0.f}; S[i][j] = z; } \
  _Pragma("unroll") for (int kk = 0; kk < 2; ++kk) \
    _Pragma("unroll") for (int i = 0; i < 4; ++i) \
      _Pragma("unroll") for (int j = 0; j < 2; ++j) \
        S[i][j] = __builtin_amdgcn_mfma_f32_16x16x32_bf16(aq[i][kk], BK[j][kk], S[i][j], 0, 0, 0); \
} while (0)

#define SOFTPV(S, CC) do { \
  /* tree max per key column (depth ~4) */ \
  float p0[4], p1[4]; \
  _Pragma("unroll") for (int i = 0; i < 4; ++i) { \
    p0[i] = fmaxf(fmaxf(S[i][0][0], S[i][0][1]), fmaxf(S[i][0][2], S[i][0][3])); \
    p1[i] = fmaxf(fmaxf(S[i][1][0], S[i][1][1]), fmaxf(S[i][1][2], S[i][1][3])); \
  } \
  float c0 = fmaxf(fmaxf(p0[0], p0[1]), fmaxf(p0[2], p0[3])); \
  float c1 = fmaxf(fmaxf(p1[0], p1[1]), fmaxf(p1[2], p1[3])); \
  c0 = fmaxf(c0, __shfl_xor(c0, 16)); c0 = fmaxf(c0, __shfl_xor(c0, 32)); \
  c1 = fmaxf(c1, __shfl_xor(c1, 16)); c1 = fmaxf(c1, __shfl_xor(c1, 32)); \
  _Pragma("unroll") for (int i = 0; i < 4; ++i) \
    _Pragma("unroll") for (int r = 0; r < 4; ++r) { \
      int qq = i * 16 + lq * 4 + r; \
      wsl[qq][lr] = pack_hu(__expf(S[i][0][r] - c0), __expf(S[i][1][r] - c1)); } \
  short8 av_[4]; \
  _Pragma("unroll") for (int ct = 0; ct < 4; ++ct) { \
    int frow = ct * 16 + lr; \
    av_[ct] = *(const short8*)&v_t[frow * 256 + ((((CC) * 4 + lq) ^ (frow & 7)) << 3)]; } \
  _Pragma("unroll") for (int qi = 0; qi < 4; ++qi) { \
    short8 bw = *(const short8*)&wsl[qi * 16 + lr][lq * 4]; \
    acc_den[qi] = __builtin_amdgcn_mfma_f32_16x16x32_bf16(ones, bw, acc_den[qi], 0, 0, 0); \
    _Pragma("unroll") for (int ct = 0; ct < 4; ++ct) \
      acc_pv[qi][ct] = __builtin_amdgcn_mfma_f32_16x16x32_bf16(av_[ct], bw, acc_pv[qi][ct], 0, 0, 0); } \
} while (0)

  // prologue: K chunks 0,1 in regs; scores for chunk 0
  LOADK(bk0, 0);
  LOADK(bk1, 1);
  QKT(sA, bk0);

  // 2-deep pipeline, unrolled (named banks; no runtime indexing)
  LOADK(bk0, 2); QKT(sB, bk1); SOFTPV(sA, 0);
  LOADK(bk1, 3); QKT(sA, bk0); SOFTPV(sB, 1);
  LOADK(bk0, 4); QKT(sB, bk1); SOFTPV(sA, 2);
  LOADK(bk1, 5); QKT(sA, bk0); SOFTPV(sB, 3);
  LOADK(bk0, 6); QKT(sB, bk1); SOFTPV(sA, 4);
  LOADK(bk1, 7); QKT(sA, bk0); SOFTPV(sB, 5);
                 QKT(sB, bk1); SOFTPV(sA, 6);
                               SOFTPV(sB, 7);

  // ---- epilogue: out[q][f] = num/den, packed 8B stores
#pragma unroll
  for (int qi = 0; qi < 4; ++qi) {
    float inv = 1.0f / (acc_den[qi][0] + 1e-10f);
    long orow = (qrow0 + qi * 16 + lr) * 1024 + hc;
#pragma unroll
    for (int ct = 0; ct < 4; ++ct) {
      uint2 p;
      p.x = pack_hu(acc_pv[qi][ct][0] * inv, acc_pv[qi][ct][1] * inv);
      p.y = pack_hu(acc_pv[qi][ct][2] * inv, acc_pv[qi][ct][3] * inv);
      *(uint2*)&attout[orow + ct * 16 + lq * 4] = p;
    }
  }
}

extern "C" void kernel_launch(void* const* d_in, const int* in_sizes, int n_in,
                              void* d_out, int out_size, void* d_ws, size_t ws_size,
                              hipStream_t stream) {
  (void)in_sizes; (void)n_in; (void)out_size; (void)ws_size;
  const float* x    = (const float*)d_in[0];
  const float* Wqkv = (const float*)d_in[1];
  const float* Wout = (const float*)d_in[2];
  float* out = (float*)d_out;
  char* ws = (char*)d_ws;

  // workspace layout (80 MB). xb aliases attout: xb is dead before attn writes.
  unsigned short* xb     = (unsigned short*)(ws);               // 33,554,432 B
  unsigned short* attout = (unsigned short*)(ws);               // (same region)
  unsigned short* wqkvb  = (unsigned short*)(ws + 33554432);    //  6,291,456 B
  unsigned short* woutb  = (unsigned short*)(ws + 39845888);    //  2,097,152 B
  unsigned short* qbuf   = (unsigned short*)(ws + 41943040);    // 33,554,432 B
  unsigned short* kbuf   = (unsigned short*)(ws + 75497472);    //  4,194,304 B
  unsigned short* vtb    = (unsigned short*)(ws + 79691776);    //  4,194,304 B

  cvt_kernel<<<16384, 256, 0, stream>>>(x, xb, 16777216);
  cvt_kernel<<<3072, 256, 0, stream>>>(Wqkv, wqkvb, 3 * 1024 * 1024);
  cvt_kernel<<<1024, 256, 0, stream>>>(Wout, woutb, 1024 * 1024);

  // Q = (x @ Wq^T) * hd^-0.5  -> qbuf (8-phase 256^2)
  gemm8p<false><<<dim3(64, 4), 512, 0, stream>>>(xb, wqkvb, (void*)qbuf, 0.125f);
  // K,V at dilated rows (every 8th): K -> kbuf [2048][1024], V -> vtb (sigma V^T)
  gemm_bt<2><<<dim3(16, 16), 256, 0, stream>>>(
      xb, wqkvb + 1024 * 1024, (void*)kbuf, vtb, 1.0f, 8192, 1024, 1024);

  attn_kernel<<<512, 512, 0, stream>>>(qbuf, kbuf, vtb, attout);

  // final projection: out = attout @ Wout^T (f32 output, 8-phase 256^2)
  gemm8p<true><<<dim3(64, 4), 512, 0, stream>>>(attout, woutb, (void*)out, 1.0f);
}

// Round 16
// 163.171 us; speedup vs baseline: 1.0697x; 1.0291x over previous
//
#include <hip/hip_runtime.h>
#include <hip/hip_bf16.h>
#include <stdint.h>

// Problem constants: B=2, M=8192, D=1024, H=16, hd=64, SEG=2048, DIL=8
// => S=4 segments, Kn=256 dilated keys/segment, nb=32 query blocks of 64.

typedef __attribute__((ext_vector_type(8))) short short8;
typedef __attribute__((ext_vector_type(4))) float f32x4;

#define DEVI static __device__ __forceinline__

DEVI unsigned short f2bf(float f) {
  union { float f; uint32_t u; } v; v.f = f;
  return (unsigned short)((v.u + 0x7FFFu + ((v.u >> 16) & 1u)) >> 16);
}

// RNE pair pack (epilogue-quality).
DEVI uint32_t pack_bf16(float lo, float hi) {
  return (uint32_t)f2bf(lo) | ((uint32_t)f2bf(hi) << 16);
}

// Round-half-up pair pack (hot paths): 5 VALU ops vs ~10. Ties-only diff.
DEVI uint32_t pack_hu(float lo, float hi) {
  union { float f; uint32_t u; } a, b; a.f = lo; b.f = hi;
  return ((a.u + 0x8000u) >> 16) | ((b.u + 0x8000u) & 0xFFFF0000u);
}

DEVI void gload_lds16(const void* g, void* l) {
  __builtin_amdgcn_global_load_lds((const __attribute__((address_space(1))) void*)g,
                                   (__attribute__((address_space(3))) void*)l,
                                   16, 0, 0);
}

// ---------------- merged f32 -> bf16 convert (x, Wqkv, Wout in one launch) ---
__global__ void cvt_all(const float* __restrict__ x, const float* __restrict__ wqkv,
                        const float* __restrict__ wout,
                        unsigned short* __restrict__ xb, unsigned short* __restrict__ wqkvb,
                        unsigned short* __restrict__ woutb) {
  long i = ((long)blockIdx.x * 256 + threadIdx.x) * 4;   // 20,971,520 elems total
  const float* src; unsigned short* dst; long off;
  if (i < 16777216)          { src = x;    dst = xb;    off = i; }
  else if (i < 19922944)     { src = wqkv; dst = wqkvb; off = i - 16777216; }
  else                       { src = wout; dst = woutb; off = i - 19922944; }
  float4 f = *(const float4*)(src + off);
  uint2 o;
  o.x = (uint32_t)f2bf(f.x) | ((uint32_t)f2bf(f.y) << 16);
  o.y = (uint32_t)f2bf(f.z) | ((uint32_t)f2bf(f.w) << 16);
  *(uint2*)(dst + off) = o;
}

// ======== 8-phase 256x256 GEMM: r12 schedule (proven best) ========
// 512 threads = 8 waves (2M x 4N); per-wave C 128x64, rows/cols interleaved
// across tile halves; gray-code quadrants. A-frags reload q=0,2 (8 rds),
// B-halves both resident, loaded q=0,1 (4 rds) -> 48 ds_read_b128/iter.
// Rhythm: {ds_read; stage; BAR; lgkm0+schedbar; prio1 MFMA16 prio0; [vmcnt]; BAR}
// Batch stages (4 gloads) at p0,p2,p4,p6; waits vmcnt(4) at p0,p3,p4,p7;
// tail t=7: p4 vmcnt(0). Per-unit retire/overwrite margins verified (r12).
// OUT_F32 epilogue: per-wave LDS transpose -> coalesced float4 stores.
#define STAGE_A(bf, hf, kt) do { \
  gload_lds16(Abase + (long)((hf) * 128 + srow0) * 1024 + (kt) * 64 + scol0, &smA[bf][hf][se0]); \
  gload_lds16(Abase + (long)((hf) * 128 + srow1) * 1024 + (kt) * 64 + scol1, &smA[bf][hf][se1]); \
} while (0)
#define STAGE_B(bf, hf, kt) do { \
  gload_lds16(Bbase + (long)((hf) * 128 + srow0) * 1024 + (kt) * 64 + scol0, &smB[bf][hf][se0]); \
  gload_lds16(Bbase + (long)((hf) * 128 + srow1) * 1024 + (kt) * 64 + scol1, &smB[bf][hf][se1]); \
} while (0)

template<bool OUT_F32>
__global__ __launch_bounds__(512, 1) void gemm8p(
    const unsigned short* __restrict__ A, const unsigned short* __restrict__ B,
    void* __restrict__ Cv, float scale)
{
  __shared__ unsigned short smA[2][2][128 * 64];   // [buf][half][r][k] swizzled
  __shared__ unsigned short smB[2][2][128 * 64];
  const int tid = threadIdx.x;
  const int tm = blockIdx.x, tn = blockIdx.y;
  const int w = tid >> 6, lane = tid & 63;
  const int wm = w >> 2, wn = w & 3;
  const int lr = lane & 15, lq = lane >> 4;

  const int e0 = tid * 8,        e1 = (512 + tid) * 8;
  const int srow0 = e0 >> 6,     srow1 = e1 >> 6;
  const int sc0 = (e0 >> 3) & 7, sc1 = (e1 >> 3) & 7;
  const int scol0 = (sc0 ^ (srow0 & 7)) * 8, scol1 = (sc1 ^ (srow1 & 7)) * 8;
  const int se0 = e0, se1 = e1;

  const unsigned short* Abase = A + (long)tm * 256 * 1024;
  const unsigned short* Bbase = B + (long)tn * 256 * 1024;

  f32x4 acc[8][4] = {};
  short8 af[4][2];        // current A-half fragments (persist 2 phases)
  short8 bfr[2][2][2];    // BOTH B-half fragments [half][nj2][kk]

  // prologue: stage tile 0 into buf0 (A0,B0 first 4 loads; B1,A1 next 4)
  STAGE_A(0, 0, 0); STAGE_B(0, 0, 0); STAGE_B(0, 1, 0); STAGE_A(0, 1, 0);
  asm volatile("s_waitcnt vmcnt(4)" ::: "memory");
  __builtin_amdgcn_s_barrier();
  asm volatile("" ::: "memory");

  for (int t = 0; t < 8; ++t) {
#pragma unroll
    for (int p = 0; p < 8; ++p) {
      const int o = p >> 2;            // LDS buf: 0 for kt=2t, 1 for kt=2t+1
      const int q = p & 3;
      const int a = (p >> 1) & 1;      // A-half: 0,0,1,1
      const int b = a ^ (q & 1);       // B-half: 0,1,1,0 (gray)

      // ---- ds_read only NEW fragments for this phase
      if (q == 0 || q == 2) {          // new A-half (8 x b128)
#pragma unroll
        for (int mi2 = 0; mi2 < 4; ++mi2) {
          int r = wm * 64 + mi2 * 16 + lr;
#pragma unroll
          for (int kk = 0; kk < 2; ++kk) {
            int kc = kk * 4 + lq;
            af[mi2][kk] = *(const short8*)&smA[o][a][r * 64 + ((kc ^ (r & 7)) * 8)];
          }
        }
      }
      if (q == 0 || q == 1) {          // new B-half b (4 x b128), kept resident
#pragma unroll
        for (int nj2 = 0; nj2 < 2; ++nj2) {
          int r = wn * 32 + nj2 * 16 + lr;
#pragma unroll
          for (int kk = 0; kk < 2; ++kk) {
            int kc = kk * 4 + lq;
            bfr[b][nj2][kk] = *(const short8*)&smB[o][b][r * 64 + ((kc ^ (r & 7)) * 8)];
          }
        }
      }

      // ---- batch stage (2 units = 4 gloads) at p0,p2,p4,p6
      switch (p) {
        case 0: STAGE_A(1, 0, 2 * t + 1); STAGE_B(1, 0, 2 * t + 1); break;
        case 2: STAGE_B(1, 1, 2 * t + 1); STAGE_A(1, 1, 2 * t + 1); break;
        case 4: if (t < 7) { STAGE_A(0, 0, 2 * t + 2); STAGE_B(0, 0, 2 * t + 2); } break;
        case 6: if (t < 7) { STAGE_B(0, 1, 2 * t + 2); STAGE_A(0, 1, 2 * t + 2); } break;
      }

      // ---- first barrier; drain ds_reads; MFMA
      __builtin_amdgcn_s_barrier();
      if (q != 3) {
        asm volatile("s_waitcnt lgkmcnt(0)" ::: "memory");
        __builtin_amdgcn_sched_barrier(0);
      }

      __builtin_amdgcn_s_setprio(1);
#pragma unroll
      for (int kk = 0; kk < 2; ++kk)
#pragma unroll
        for (int mi2 = 0; mi2 < 4; ++mi2)
#pragma unroll
          for (int nj2 = 0; nj2 < 2; ++nj2)
            acc[a * 4 + mi2][b * 2 + nj2] = __builtin_amdgcn_mfma_f32_16x16x32_bf16(
                af[mi2][kk], bfr[b][nj2][kk], acc[a * 4 + mi2][b * 2 + nj2], 0, 0, 0);
      __builtin_amdgcn_s_setprio(0);

      // ---- counted wait (p0,p3,p4,p7) + second barrier
      if (t < 7) {
        if (p == 0 || p == 3 || p == 4 || p == 7)
          asm volatile("s_waitcnt vmcnt(4)" ::: "memory");
      } else {
        if (p == 0 || p == 3)  asm volatile("s_waitcnt vmcnt(4)" ::: "memory");
        else if (p == 4)       asm volatile("s_waitcnt vmcnt(0)" ::: "memory");
      }
      __builtin_amdgcn_s_barrier();
      asm volatile("" ::: "memory");
    }
  }

  // ---- epilogue
  if (OUT_F32) {
    // per-wave LDS transpose -> coalesced float4 stores (full 128B lines).
    float* scratch = (float*)&smA[0][0][0] + w * 544;   // 16*33=528 f32/wave
    float* Cf = (float*)Cv;
#pragma unroll
    for (int ai = 0; ai < 8; ++ai) {
#pragma unroll
      for (int b2 = 0; b2 < 2; ++b2) {
#pragma unroll
        for (int nj2 = 0; nj2 < 2; ++nj2)
#pragma unroll
          for (int rr = 0; rr < 4; ++rr)
            scratch[(lq * 4 + rr) * 33 + nj2 * 16 + lr] = acc[ai][b2 * 2 + nj2][rr] * scale;
        asm volatile("s_waitcnt lgkmcnt(0)" ::: "memory");
        __builtin_amdgcn_sched_barrier(0);
        int rr2 = lane >> 2, cb = (lane & 3) * 8;
        float4 v0, v1;
        v0.x = scratch[rr2 * 33 + cb + 0]; v0.y = scratch[rr2 * 33 + cb + 1];
        v0.z = scratch[rr2 * 33 + cb + 2]; v0.w = scratch[rr2 * 33 + cb + 3];
        v1.x = scratch[rr2 * 33 + cb + 4]; v1.y = scratch[rr2 * 33 + cb + 5];
        v1.z = scratch[rr2 * 33 + cb + 6]; v1.w = scratch[rr2 * 33 + cb + 7];
        asm volatile("s_waitcnt lgkmcnt(0)" ::: "memory");
        __builtin_amdgcn_sched_barrier(0);
        long rowg = tm * 256 + wm * 64 + (ai & 3) * 16 + (ai >> 2) * 128 + rr2;
        long colg = tn * 256 + wn * 32 + b2 * 128 + cb;
        *(float4*)&Cf[rowg * 1024 + colg] = v0;
        *(float4*)&Cf[rowg * 1024 + colg + 4] = v1;
      }
    }
  } else {
    const int row0 = tm * 256 + wm * 64 + lq * 4;
    const int col0 = tn * 256 + wn * 32 + lr;
#pragma unroll
    for (int mi = 0; mi < 8; ++mi) {
      int row = row0 + (mi & 3) * 16 + (mi >> 2) * 128;
#pragma unroll
      for (int nj = 0; nj < 4; ++nj) {
        int col = col0 + (nj & 1) * 16 + (nj >> 1) * 128;
#pragma unroll
        for (int rr = 0; rr < 4; ++rr)
          ((unsigned short*)Cv)[(long)(row + rr) * 1024 + col] = f2bf(acc[mi][nj][rr] * scale);
      }
    }
  }
}

// ---------------- 128^2 GEMM for the KV split (bf16 A from xb) ----------------
// EPI 2: tn<8 -> bf16 K rows to Cv; tn>=8 -> V TRANSPOSED + sigma-permuted to
// Cv2 (row = seg*1024+f; u32 col c packs tokens (32*(c>>4)+(c&15), +16)).
template<int EPI>
__global__ __launch_bounds__(256, 2) void gemm_bt(
    const unsigned short* __restrict__ A, const unsigned short* __restrict__ B,
    void* __restrict__ Cv, unsigned short* __restrict__ Cv2,
    float scale, long a_row_stride, int ldc, int K)
{
  __shared__ unsigned short smA[128 * 64];
  __shared__ unsigned short smB[128 * 64];
  const int tid = threadIdx.x;
  const int tm = blockIdx.x, tn = blockIdx.y;
  const int w = tid >> 6, lane = tid & 63;
  const int wr = (w >> 1) * 64, wc = (w & 1) * 64;
  const int lr = lane & 15, lq = lane >> 4;

  int se[4], srow[4], scol[4];
#pragma unroll
  for (int i = 0; i < 4; ++i) {
    int e = (i * 256 + tid) * 8;
    int r = e >> 6;
    int cc = (e >> 3) & 7;
    se[i] = e; srow[i] = r; scol[i] = (cc ^ (r & 7)) * 8;
  }

  f32x4 acc[4][4] = {};

  for (int kt = 0; kt < K / 64; ++kt) {
    if (kt) __syncthreads();
#pragma unroll
    for (int i = 0; i < 4; ++i)
      gload_lds16(A + (long)(tm * 128 + srow[i]) * a_row_stride + kt * 64 + scol[i], &smA[se[i]]);
#pragma unroll
    for (int i = 0; i < 4; ++i)
      gload_lds16(B + (long)(tn * 128 + srow[i]) * K + kt * 64 + scol[i], &smB[se[i]]);
    __syncthreads();

#pragma unroll
    for (int kk = 0; kk < 2; ++kk) {
      int kc = kk * 4 + lq;
      short8 af[4], bfm[4];
#pragma unroll
      for (int i = 0; i < 4; ++i) {
        int row = wr + i * 16 + lr;
        af[i] = *(const short8*)&smA[row * 64 + ((kc ^ (row & 7)) * 8)];
      }
#pragma unroll
      for (int j = 0; j < 4; ++j) {
        int row = wc + j * 16 + lr;
        bfm[j] = *(const short8*)&smB[row * 64 + ((kc ^ (row & 7)) * 8)];
      }
#pragma unroll
      for (int i = 0; i < 4; ++i)
#pragma unroll
        for (int j = 0; j < 4; ++j)
          acc[i][j] = __builtin_amdgcn_mfma_f32_16x16x32_bf16(af[i], bfm[j], acc[i][j], 0, 0, 0);
    }
  }

  if (EPI == 2 && tn >= 8) {
    const int fbase = (tn - 8) * 128 + wc;
#pragma unroll
    for (int ip = 0; ip < 4; ip += 2) {
      int t0 = tm * 128 + wr + ip * 16 + lq * 4;
      int seg = t0 >> 8;
      int ts  = t0 & 255;
      int c32 = (ts >> 5) * 16 + (ts & 15);
#pragma unroll
      for (int j = 0; j < 4; ++j) {
        int f = fbase + j * 16 + lr;
        uint32_t* rp = (uint32_t*)&Cv2[((long)(seg * 1024 + f)) * 256];
        uint4 U;
        U.x = pack_bf16(acc[ip][j][0] * scale, acc[ip + 1][j][0] * scale);
        U.y = pack_bf16(acc[ip][j][1] * scale, acc[ip + 1][j][1] * scale);
        U.z = pack_bf16(acc[ip][j][2] * scale, acc[ip + 1][j][2] * scale);
        U.w = pack_bf16(acc[ip][j][3] * scale, acc[ip + 1][j][3] * scale);
        *(uint4*)&rp[c32] = U;
      }
    }
    return;
  }

#pragma unroll
  for (int i = 0; i < 4; ++i) {
    int rg0 = tm * 128 + wr + i * 16 + lq * 4;
#pragma unroll
    for (int j = 0; j < 4; ++j) {
      int cg = tn * 128 + wc + j * 16 + lr;
#pragma unroll
      for (int r = 0; r < 4; ++r) {
        float v = acc[i][j][r] * scale;
        long off = (long)(rg0 + r) * ldc + cg;
        if (EPI == 0) ((float*)Cv)[off] = v;
        else          ((unsigned short*)Cv)[off] = f2bf(v);
      }
    }
  }
}

// ---------------- segment-local dilated attention, 2-deep pipeline ----------
// r15 structure; SOFTPV now pipelines the w LDS roundtrip per 16-row block:
// {exp+pack rows u; 4 ds_writes; read bw_u; den+PV MFMA_u} -- in-order LDS
// completion means read_u waits only writes <= u, and block-u's MFMAs overlap
// block-(u+1)'s exp/pack VALU (was: one big write-drain before all reads).
__global__ __launch_bounds__(512, 2) void attn_kernel(
    const unsigned short* __restrict__ qb,    // [16384][1024] bf16, q*scale
    const unsigned short* __restrict__ kb,    // [2048][1024] bf16 dilated keys
    const unsigned short* __restrict__ vtb,   // sigma-permuted V^T
    unsigned short* __restrict__ attout)      // [16384][1024] bf16, col = h*64+d
{
  __shared__ unsigned short v_t[64 * 256];    // [f][g] swizzled, 32 KB
  __shared__ uint32_t w32[8][64][20];         // per-wave [q][col] slices, 40 KB

  const int u = (blockIdx.x & 7) * 64 + (blockIdx.x >> 3);
  const int quarter = u & 3, h = (u >> 2) & 15, s = (u >> 6) & 3, b = u >> 8;
  const int tid = threadIdx.x, w = tid >> 6, lane = tid & 63;
  const int lr = lane & 15, lq = lane >> 4;
  const long qrow0 = (long)b * 8192 + s * 2048 + quarter * 512 + w * 64;
  const int hc = h * 64;

  const unsigned short* kbase = kb + ((long)(b * 4 + s) * 256) * 1024 + hc;
  const unsigned short* vbase = vtb + ((long)(b * 4 + s) * 1024 + hc) * 256;

#pragma unroll
  for (int it = 0; it < 4; ++it) {
    int e = (it * 512 + tid) * 8;
    int f = e >> 8;
    int ch = (e >> 3) & 31;
    gload_lds16(vbase + (long)f * 256 + ((ch ^ (f & 7)) * 8), &v_t[e]);
  }

  const unsigned short* qbase = qb + qrow0 * 1024 + hc;
  short8 aq[4][2];
#pragma unroll
  for (int i = 0; i < 4; ++i)
#pragma unroll
    for (int kk = 0; kk < 2; ++kk)
      aq[i][kk] = *(const short8*)&qbase[(i * 16 + lr) * 1024 + (kk * 4 + lq) * 8];

  __syncthreads();   // V staged (only barrier in the kernel)

  short8 ones;
#pragma unroll
  for (int e = 0; e < 8; ++e) ones[e] = (short)0x3F80;  // bf16 1.0

  uint32_t (*wsl)[20] = w32[w];

  f32x4 acc_pv[4][4] = {};
  f32x4 acc_den[4] = {};
  short8 bk0[2][2], bk1[2][2];
  f32x4 sA[4][2], sB[4][2];

#define LOADK(BK, CC) do { \
  _Pragma("unroll") for (int j = 0; j < 2; ++j) \
    _Pragma("unroll") for (int kk = 0; kk < 2; ++kk) \
      BK[j][kk] = *(const short8*)&kbase[(long)((CC) * 32 + j * 16 + lr) * 1024 + (kk * 4 + lq) * 8]; \
} while (0)

#define QKT(S, BK) do { \
  _Pragma("unroll") for (int i = 0; i < 4; ++i) \
    _Pragma("unroll") for (int j = 0; j < 2; ++j) { \
      f32x4 z = {0.f, 0.f, 0.f, 0.f}; S[i][j] = z; } \
  _Pragma("unroll") for (int kk = 0; kk < 2; ++kk) \
    _Pragma("unroll") for (int i = 0; i < 4; ++i) \
      _Pragma("unroll") for (int j = 0; j < 2; ++j) \
        S[i][j] = __builtin_amdgcn_mfma_f32_16x16x32_bf16(aq[i][kk], BK[j][kk], S[i][j], 0, 0, 0); \
} while (0)

#define SOFTPV(S, CC) do { \
  /* V^T fragment reads issued early (independent LDS reads) */ \
  short8 av_[4]; \
  _Pragma("unroll") for (int ct = 0; ct < 4; ++ct) { \
    int frow = ct * 16 + lr; \
    av_[ct] = *(const short8*)&v_t[frow * 256 + ((((CC) * 4 + lq) ^ (frow & 7)) << 3)]; } \
  /* tree max per key column (depth ~4) over ALL 64 queries */ \
  float p0[4], p1[4]; \
  _Pragma("unroll") for (int i = 0; i < 4; ++i) { \
    p0[i] = fmaxf(fmaxf(S[i][0][0], S[i][0][1]), fmaxf(S[i][0][2], S[i][0][3])); \
    p1[i] = fmaxf(fmaxf(S[i][1][0], S[i][1][1]), fmaxf(S[i][1][2], S[i][1][3])); \
  } \
  float c0 = fmaxf(fmaxf(p0[0], p0[1]), fmaxf(p0[2], p0[3])); \
  float c1 = fmaxf(fmaxf(p1[0], p1[1]), fmaxf(p1[2], p1[3])); \
  c0 = fmaxf(c0, __shfl_xor(c0, 16)); c0 = fmaxf(c0, __shfl_xor(c0, 32)); \
  c1 = fmaxf(c1, __shfl_xor(c1, 16)); c1 = fmaxf(c1, __shfl_xor(c1, 32)); \
  /* per-16-row block: exp+pack -> write -> read -> MFMA (pipelined) */ \
  _Pragma("unroll") for (int uu = 0; uu < 4; ++uu) { \
    _Pragma("unroll") for (int r = 0; r < 4; ++r) { \
      int qq = uu * 16 + lq * 4 + r; \
      wsl[qq][lr] = pack_hu(__expf(S[uu][0][r] - c0), __expf(S[uu][1][r] - c1)); } \
    short8 bw = *(const short8*)&wsl[uu * 16 + lr][lq * 4]; \
    acc_den[uu] = __builtin_amdgcn_mfma_f32_16x16x32_bf16(ones, bw, acc_den[uu], 0, 0, 0); \
    _Pragma("unroll") for (int ct = 0; ct < 4; ++ct) \
      acc_pv[uu][ct] = __builtin_amdgcn_mfma_f32_16x16x32_bf16(av_[ct], bw, acc_pv[uu][ct], 0, 0, 0); \
  } \
} while (0)

  // prologue: K chunks 0,1 in regs; scores for chunk 0
  LOADK(bk0, 0);
  LOADK(bk1, 1);
  QKT(sA, bk0);

  // 2-deep pipeline, unrolled (named banks; no runtime indexing)
  LOADK(bk0, 2); QKT(sB, bk1); SOFTPV(sA, 0);
  LOADK(bk1, 3); QKT(sA, bk0); SOFTPV(sB, 1);
  LOADK(bk0, 4); QKT(sB, bk1); SOFTPV(sA, 2);
  LOADK(bk1, 5); QKT(sA, bk0); SOFTPV(sB, 3);
  LOADK(bk0, 6); QKT(sB, bk1); SOFTPV(sA, 4);
  LOADK(bk1, 7); QKT(sA, bk0); SOFTPV(sB, 5);
                 QKT(sB, bk1); SOFTPV(sA, 6);
                               SOFTPV(sB, 7);

  // ---- epilogue: out[q][f] = num/den, packed 8B stores
#pragma unroll
  for (int qi = 0; qi < 4; ++qi) {
    float inv = 1.0f / (acc_den[qi][0] + 1e-10f);
    long orow = (qrow0 + qi * 16 + lr) * 1024 + hc;
#pragma unroll
    for (int ct = 0; ct < 4; ++ct) {
      uint2 p;
      p.x = pack_hu(acc_pv[qi][ct][0] * inv, acc_pv[qi][ct][1] * inv);
      p.y = pack_hu(acc_pv[qi][ct][2] * inv, acc_pv[qi][ct][3] * inv);
      *(uint2*)&attout[orow + ct * 16 + lq * 4] = p;
    }
  }
}

extern "C" void kernel_launch(void* const* d_in, const int* in_sizes, int n_in,
                              void* d_out, int out_size, void* d_ws, size_t ws_size,
                              hipStream_t stream) {
  (void)in_sizes; (void)n_in; (void)out_size; (void)ws_size;
  const float* x    = (const float*)d_in[0];
  const float* Wqkv = (const float*)d_in[1];
  const float* Wout = (const float*)d_in[2];
  float* out = (float*)d_out;
  char* ws = (char*)d_ws;

  // workspace layout (80 MB). xb aliases attout: xb is dead before attn writes.
  unsigned short* xb     = (unsigned short*)(ws);               // 33,554,432 B
  unsigned short* attout = (unsigned short*)(ws);               // (same region)
  unsigned short* wqkvb  = (unsigned short*)(ws + 33554432);    //  6,291,456 B
  unsigned short* woutb  = (unsigned short*)(ws + 39845888);    //  2,097,152 B
  unsigned short* qbuf   = (unsigned short*)(ws + 41943040);    // 33,554,432 B
  unsigned short* kbuf   = (unsigned short*)(ws + 75497472);    //  4,194,304 B
  unsigned short* vtb    = (unsigned short*)(ws + 79691776);    //  4,194,304 B

  // one merged conversion launch: x (16.7M) + Wqkv (3.1M) + Wout (1.0M)
  cvt_all<<<20480, 256, 0, stream>>>(x, Wqkv, Wout, xb, wqkvb, woutb);

  // Q = (x @ Wq^T) * hd^-0.5  -> qbuf (8-phase 256^2)
  gemm8p<false><<<dim3(64, 4), 512, 0, stream>>>(xb, wqkvb, (void*)qbuf, 0.125f);
  // K,V at dilated rows (every 8th): K -> kbuf [2048][1024], V -> vtb (sigma V^T)
  gemm_bt<2><<<dim3(16, 16), 256, 0, stream>>>(
      xb, wqkvb + 1024 * 1024, (void*)kbuf, vtb, 1.0f, 8192, 1024, 1024);

  attn_kernel<<<512, 512, 0, stream>>>(qbuf, kbuf, vtb, attout);

  // final projection: out = attout @ Wout^T (f32 output, 8-phase 256^2)
  gemm8p<true><<<dim3(64, 4), 512, 0, stream>>>(attout, woutb, (void*)out, 1.0f);
}

// Round 17
// 162.728 us; speedup vs baseline: 1.0726x; 1.0027x over previous
//
#include <hip/hip_runtime.h>
#include <hip/hip_bf16.h>
#include <stdint.h>

// Problem constants: B=2, M=8192, D=1024, H=16, hd=64, SEG=2048, DIL=8
// => S=4 segments, Kn=256 dilated keys/segment, nb=32 query blocks of 64.

typedef __attribute__((ext_vector_type(8))) short short8;
typedef __attribute__((ext_vector_type(4))) float f32x4;

#define DEVI static __device__ __forceinline__

DEVI unsigned short f2bf(float f) {
  union { float f; uint32_t u; } v; v.f = f;
  return (unsigned short)((v.u + 0x7FFFu + ((v.u >> 16) & 1u)) >> 16);
}

// RNE pair pack (epilogue-quality).
DEVI uint32_t pack_bf16(float lo, float hi) {
  return (uint32_t)f2bf(lo) | ((uint32_t)f2bf(hi) << 16);
}

// Round-half-up pair pack (hot paths): 5 VALU ops vs ~10. Ties-only diff.
DEVI uint32_t pack_hu(float lo, float hi) {
  union { float f; uint32_t u; } a, b; a.f = lo; b.f = hi;
  return ((a.u + 0x8000u) >> 16) | ((b.u + 0x8000u) & 0xFFFF0000u);
}

DEVI void gload_lds16(const void* g, void* l) {
  __builtin_amdgcn_global_load_lds((const __attribute__((address_space(1))) void*)g,
                                   (__attribute__((address_space(3))) void*)l,
                                   16, 0, 0);
}

// ---------------- merged f32 -> bf16 convert (x, Wqkv, Wout in one launch) ---
__global__ void cvt_all(const float* __restrict__ x, const float* __restrict__ wqkv,
                        const float* __restrict__ wout,
                        unsigned short* __restrict__ xb, unsigned short* __restrict__ wqkvb,
                        unsigned short* __restrict__ woutb) {
  long i = ((long)blockIdx.x * 256 + threadIdx.x) * 4;   // 20,971,520 elems total
  const float* src; unsigned short* dst; long off;
  if (i < 16777216)          { src = x;    dst = xb;    off = i; }
  else if (i < 19922944)     { src = wqkv; dst = wqkvb; off = i - 16777216; }
  else                       { src = wout; dst = woutb; off = i - 19922944; }
  float4 f = *(const float4*)(src + off);
  uint2 o;
  o.x = (uint32_t)f2bf(f.x) | ((uint32_t)f2bf(f.y) << 16);
  o.y = (uint32_t)f2bf(f.z) | ((uint32_t)f2bf(f.w) << 16);
  *(uint2*)(dst + off) = o;
}

// ======== 8-phase 256x256 GEMM: r12 schedule, compiler-managed lgkm ========
// 512 threads = 8 waves (2M x 4N); per-wave C 128x64, rows/cols interleaved
// across tile halves; gray-code quadrants. A-frags reload q=0,2 (8 rds),
// B-halves both resident, loaded q=0,1 (4 rds) -> 48 ds_read_b128/iter.
// r17 change: the manual {lgkmcnt(0); sched_barrier(0)} before the MFMA
// cluster is REMOVED -- those ds_reads are compiler-generated loads with
// dataflow edges, so hipcc emits fine-grained lgkmcnt(N) per MFMA (guide
// m97 asm note); the full drain + scheduling pin was defeating that and
// serializing read-latency in front of every MFMA cluster. The zero-cost
// `"memory"` fence after each s_barrier keeps LDS ops from hoisting across
// barriers, preserving r12's verified cross-wave RAW/WAR discipline.
// Batch stages (4 gloads) at p0,p2,p4,p6; waits vmcnt(4) at p0,p3,p4,p7;
// tail t=7: p4 vmcnt(0).
// OUT_F32 epilogue: per-wave LDS transpose -> coalesced float4 stores.
#define STAGE_A(bf, hf, kt) do { \
  gload_lds16(Abase + (long)((hf) * 128 + srow0) * 1024 + (kt) * 64 + scol0, &smA[bf][hf][se0]); \
  gload_lds16(Abase + (long)((hf) * 128 + srow1) * 1024 + (kt) * 64 + scol1, &smA[bf][hf][se1]); \
} while (0)
#define STAGE_B(bf, hf, kt) do { \
  gload_lds16(Bbase + (long)((hf) * 128 + srow0) * 1024 + (kt) * 64 + scol0, &smB[bf][hf][se0]); \
  gload_lds16(Bbase + (long)((hf) * 128 + srow1) * 1024 + (kt) * 64 + scol1, &smB[bf][hf][se1]); \
} while (0)

template<bool OUT_F32>
__global__ __launch_bounds__(512, 1) void gemm8p(
    const unsigned short* __restrict__ A, const unsigned short* __restrict__ B,
    void* __restrict__ Cv, float scale)
{
  __shared__ unsigned short smA[2][2][128 * 64];   // [buf][half][r][k] swizzled
  __shared__ unsigned short smB[2][2][128 * 64];
  const int tid = threadIdx.x;
  const int tm = blockIdx.x, tn = blockIdx.y;
  const int w = tid >> 6, lane = tid & 63;
  const int wm = w >> 2, wn = w & 3;
  const int lr = lane & 15, lq = lane >> 4;

  const int e0 = tid * 8,        e1 = (512 + tid) * 8;
  const int srow0 = e0 >> 6,     srow1 = e1 >> 6;
  const int sc0 = (e0 >> 3) & 7, sc1 = (e1 >> 3) & 7;
  const int scol0 = (sc0 ^ (srow0 & 7)) * 8, scol1 = (sc1 ^ (srow1 & 7)) * 8;
  const int se0 = e0, se1 = e1;

  const unsigned short* Abase = A + (long)tm * 256 * 1024;
  const unsigned short* Bbase = B + (long)tn * 256 * 1024;

  f32x4 acc[8][4] = {};
  short8 af[4][2];        // current A-half fragments (persist 2 phases)
  short8 bfr[2][2][2];    // BOTH B-half fragments [half][nj2][kk]

  // prologue: stage tile 0 into buf0 (A0,B0 first 4 loads; B1,A1 next 4)
  STAGE_A(0, 0, 0); STAGE_B(0, 0, 0); STAGE_B(0, 1, 0); STAGE_A(0, 1, 0);
  asm volatile("s_waitcnt vmcnt(4)" ::: "memory");
  __builtin_amdgcn_s_barrier();
  asm volatile("" ::: "memory");

  for (int t = 0; t < 8; ++t) {
#pragma unroll
    for (int p = 0; p < 8; ++p) {
      const int o = p >> 2;            // LDS buf: 0 for kt=2t, 1 for kt=2t+1
      const int q = p & 3;
      const int a = (p >> 1) & 1;      // A-half: 0,0,1,1
      const int b = a ^ (q & 1);       // B-half: 0,1,1,0 (gray)

      // ---- ds_read only NEW fragments for this phase
      if (q == 0 || q == 2) {          // new A-half (8 x b128)
#pragma unroll
        for (int mi2 = 0; mi2 < 4; ++mi2) {
          int r = wm * 64 + mi2 * 16 + lr;
#pragma unroll
          for (int kk = 0; kk < 2; ++kk) {
            int kc = kk * 4 + lq;
            af[mi2][kk] = *(const short8*)&smA[o][a][r * 64 + ((kc ^ (r & 7)) * 8)];
          }
        }
      }
      if (q == 0 || q == 1) {          // new B-half b (4 x b128), kept resident
#pragma unroll
        for (int nj2 = 0; nj2 < 2; ++nj2) {
          int r = wn * 32 + nj2 * 16 + lr;
#pragma unroll
          for (int kk = 0; kk < 2; ++kk) {
            int kc = kk * 4 + lq;
            bfr[b][nj2][kk] = *(const short8*)&smB[o][b][r * 64 + ((kc ^ (r & 7)) * 8)];
          }
        }
      }

      // ---- batch stage (2 units = 4 gloads) at p0,p2,p4,p6
      switch (p) {
        case 0: STAGE_A(1, 0, 2 * t + 1); STAGE_B(1, 0, 2 * t + 1); break;
        case 2: STAGE_B(1, 1, 2 * t + 1); STAGE_A(1, 1, 2 * t + 1); break;
        case 4: if (t < 7) { STAGE_A(0, 0, 2 * t + 2); STAGE_B(0, 0, 2 * t + 2); } break;
        case 6: if (t < 7) { STAGE_B(0, 1, 2 * t + 2); STAGE_A(0, 1, 2 * t + 2); } break;
      }

      // ---- first barrier; MFMA cluster (compiler emits per-use lgkmcnt(N))
      __builtin_amdgcn_s_barrier();
      asm volatile("" ::: "memory");

      __builtin_amdgcn_s_setprio(1);
#pragma unroll
      for (int kk = 0; kk < 2; ++kk)
#pragma unroll
        for (int mi2 = 0; mi2 < 4; ++mi2)
#pragma unroll
          for (int nj2 = 0; nj2 < 2; ++nj2)
            acc[a * 4 + mi2][b * 2 + nj2] = __builtin_amdgcn_mfma_f32_16x16x32_bf16(
                af[mi2][kk], bfr[b][nj2][kk], acc[a * 4 + mi2][b * 2 + nj2], 0, 0, 0);
      __builtin_amdgcn_s_setprio(0);

      // ---- counted wait (p0,p3,p4,p7) + second barrier
      if (t < 7) {
        if (p == 0 || p == 3 || p == 4 || p == 7)
          asm volatile("s_waitcnt vmcnt(4)" ::: "memory");
      } else {
        if (p == 0 || p == 3)  asm volatile("s_waitcnt vmcnt(4)" ::: "memory");
        else if (p == 4)       asm volatile("s_waitcnt vmcnt(0)" ::: "memory");
      }
      __builtin_amdgcn_s_barrier();
      asm volatile("" ::: "memory");
    }
  }

  // ---- epilogue
  if (OUT_F32) {
    // per-wave LDS transpose -> coalesced float4 stores (full 128B lines).
    float* scratch = (float*)&smA[0][0][0] + w * 544;   // 16*33=528 f32/wave
    float* Cf = (float*)Cv;
#pragma unroll
    for (int ai = 0; ai < 8; ++ai) {
#pragma unroll
      for (int b2 = 0; b2 < 2; ++b2) {
#pragma unroll
        for (int nj2 = 0; nj2 < 2; ++nj2)
#pragma unroll
          for (int rr = 0; rr < 4; ++rr)
            scratch[(lq * 4 + rr) * 33 + nj2 * 16 + lr] = acc[ai][b2 * 2 + nj2][rr] * scale;
        asm volatile("s_waitcnt lgkmcnt(0)" ::: "memory");
        __builtin_amdgcn_sched_barrier(0);
        int rr2 = lane >> 2, cb = (lane & 3) * 8;
        float4 v0, v1;
        v0.x = scratch[rr2 * 33 + cb + 0]; v0.y = scratch[rr2 * 33 + cb + 1];
        v0.z = scratch[rr2 * 33 + cb + 2]; v0.w = scratch[rr2 * 33 + cb + 3];
        v1.x = scratch[rr2 * 33 + cb + 4]; v1.y = scratch[rr2 * 33 + cb + 5];
        v1.z = scratch[rr2 * 33 + cb + 6]; v1.w = scratch[rr2 * 33 + cb + 7];
        asm volatile("s_waitcnt lgkmcnt(0)" ::: "memory");
        __builtin_amdgcn_sched_barrier(0);
        long rowg = tm * 256 + wm * 64 + (ai & 3) * 16 + (ai >> 2) * 128 + rr2;
        long colg = tn * 256 + wn * 32 + b2 * 128 + cb;
        *(float4*)&Cf[rowg * 1024 + colg] = v0;
        *(float4*)&Cf[rowg * 1024 + colg + 4] = v1;
      }
    }
  } else {
    const int row0 = tm * 256 + wm * 64 + lq * 4;
    const int col0 = tn * 256 + wn * 32 + lr;
#pragma unroll
    for (int mi = 0; mi < 8; ++mi) {
      int row = row0 + (mi & 3) * 16 + (mi >> 2) * 128;
#pragma unroll
      for (int nj = 0; nj < 4; ++nj) {
        int col = col0 + (nj & 1) * 16 + (nj >> 1) * 128;
#pragma unroll
        for (int rr = 0; rr < 4; ++rr)
          ((unsigned short*)Cv)[(long)(row + rr) * 1024 + col] = f2bf(acc[mi][nj][rr] * scale);
      }
    }
  }
}

// ---------------- 128^2 GEMM for the KV split (bf16 A from xb) ----------------
// EPI 2: tn<8 -> bf16 K rows to Cv; tn>=8 -> V TRANSPOSED + sigma-permuted to
// Cv2 (row = seg*1024+f; u32 col c packs tokens (32*(c>>4)+(c&15), +16)).
template<int EPI>
__global__ __launch_bounds__(256, 2) void gemm_bt(
    const unsigned short* __restrict__ A, const unsigned short* __restrict__ B,
    void* __restrict__ Cv, unsigned short* __restrict__ Cv2,
    float scale, long a_row_stride, int ldc, int K)
{
  __shared__ unsigned short smA[128 * 64];
  __shared__ unsigned short smB[128 * 64];
  const int tid = threadIdx.x;
  const int tm = blockIdx.x, tn = blockIdx.y;
  const int w = tid >> 6, lane = tid & 63;
  const int wr = (w >> 1) * 64, wc = (w & 1) * 64;
  const int lr = lane & 15, lq = lane >> 4;

  int se[4], srow[4], scol[4];
#pragma unroll
  for (int i = 0; i < 4; ++i) {
    int e = (i * 256 + tid) * 8;
    int r = e >> 6;
    int cc = (e >> 3) & 7;
    se[i] = e; srow[i] = r; scol[i] = (cc ^ (r & 7)) * 8;
  }

  f32x4 acc[4][4] = {};

  for (int kt = 0; kt < K / 64; ++kt) {
    if (kt) __syncthreads();
#pragma unroll
    for (int i = 0; i < 4; ++i)
      gload_lds16(A + (long)(tm * 128 + srow[i]) * a_row_stride + kt * 64 + scol[i], &smA[se[i]]);
#pragma unroll
    for (int i = 0; i < 4; ++i)
      gload_lds16(B + (long)(tn * 128 + srow[i]) * K + kt * 64 + scol[i], &smB[se[i]]);
    __syncthreads();

#pragma unroll
    for (int kk = 0; kk < 2; ++kk) {
      int kc = kk * 4 + lq;
      short8 af[4], bfm[4];
#pragma unroll
      for (int i = 0; i < 4; ++i) {
        int row = wr + i * 16 + lr;
        af[i] = *(const short8*)&smA[row * 64 + ((kc ^ (row & 7)) * 8)];
      }
#pragma unroll
      for (int j = 0; j < 4; ++j) {
        int row = wc + j * 16 + lr;
        bfm[j] = *(const short8*)&smB[row * 64 + ((kc ^ (row & 7)) * 8)];
      }
#pragma unroll
      for (int i = 0; i < 4; ++i)
#pragma unroll
        for (int j = 0; j < 4; ++j)
          acc[i][j] = __builtin_amdgcn_mfma_f32_16x16x32_bf16(af[i], bfm[j], acc[i][j], 0, 0, 0);
    }
  }

  if (EPI == 2 && tn >= 8) {
    const int fbase = (tn - 8) * 128 + wc;
#pragma unroll
    for (int ip = 0; ip < 4; ip += 2) {
      int t0 = tm * 128 + wr + ip * 16 + lq * 4;
      int seg = t0 >> 8;
      int ts  = t0 & 255;
      int c32 = (ts >> 5) * 16 + (ts & 15);
#pragma unroll
      for (int j = 0; j < 4; ++j) {
        int f = fbase + j * 16 + lr;
        uint32_t* rp = (uint32_t*)&Cv2[((long)(seg * 1024 + f)) * 256];
        uint4 U;
        U.x = pack_bf16(acc[ip][j][0] * scale, acc[ip + 1][j][0] * scale);
        U.y = pack_bf16(acc[ip][j][1] * scale, acc[ip + 1][j][1] * scale);
        U.z = pack_bf16(acc[ip][j][2] * scale, acc[ip + 1][j][2] * scale);
        U.w = pack_bf16(acc[ip][j][3] * scale, acc[ip + 1][j][3] * scale);
        *(uint4*)&rp[c32] = U;
      }
    }
    return;
  }

#pragma unroll
  for (int i = 0; i < 4; ++i) {
    int rg0 = tm * 128 + wr + i * 16 + lq * 4;
#pragma unroll
    for (int j = 0; j < 4; ++j) {
      int cg = tn * 128 + wc + j * 16 + lr;
#pragma unroll
      for (int r = 0; r < 4; ++r) {
        float v = acc[i][j][r] * scale;
        long off = (long)(rg0 + r) * ldc + cg;
        if (EPI == 0) ((float*)Cv)[off] = v;
        else          ((unsigned short*)Cv)[off] = f2bf(v);
      }
    }
  }
}

// ---------------- segment-local dilated attention, 2-deep pipeline ----------
// (r16 structure, unchanged this round)
__global__ __launch_bounds__(512, 2) void attn_kernel(
    const unsigned short* __restrict__ qb,    // [16384][1024] bf16, q*scale
    const unsigned short* __restrict__ kb,    // [2048][1024] bf16 dilated keys
    const unsigned short* __restrict__ vtb,   // sigma-permuted V^T
    unsigned short* __restrict__ attout)      // [16384][1024] bf16, col = h*64+d
{
  __shared__ unsigned short v_t[64 * 256];    // [f][g] swizzled, 32 KB
  __shared__ uint32_t w32[8][64][20];         // per-wave [q][col] slices, 40 KB

  const int u = (blockIdx.x & 7) * 64 + (blockIdx.x >> 3);
  const int quarter = u & 3, h = (u >> 2) & 15, s = (u >> 6) & 3, b = u >> 8;
  const int tid = threadIdx.x, w = tid >> 6, lane = tid & 63;
  const int lr = lane & 15, lq = lane >> 4;
  const long qrow0 = (long)b * 8192 + s * 2048 + quarter * 512 + w * 64;
  const int hc = h * 64;

  const unsigned short* kbase = kb + ((long)(b * 4 + s) * 256) * 1024 + hc;
  const unsigned short* vbase = vtb + ((long)(b * 4 + s) * 1024 + hc) * 256;

#pragma unroll
  for (int it = 0; it < 4; ++it) {
    int e = (it * 512 + tid) * 8;
    int f = e >> 8;
    int ch = (e >> 3) & 31;
    gload_lds16(vbase + (long)f * 256 + ((ch ^ (f & 7)) * 8), &v_t[e]);
  }

  const unsigned short* qbase = qb + qrow0 * 1024 + hc;
  short8 aq[4][2];
#pragma unroll
  for (int i = 0; i < 4; ++i)
#pragma unroll
    for (int kk = 0; kk < 2; ++kk)
      aq[i][kk] = *(const short8*)&qbase[(i * 16 + lr) * 1024 + (kk * 4 + lq) * 8];

  __syncthreads();   // V staged (only barrier in the kernel)

  short8 ones;
#pragma unroll
  for (int e = 0; e < 8; ++e) ones[e] = (short)0x3F80;  // bf16 1.0

  uint32_t (*wsl)[20] = w32[w];

  f32x4 acc_pv[4][4] = {};
  f32x4 acc_den[4] = {};
  short8 bk0[2][2], bk1[2][2];
  f32x4 sA[4][2], sB[4][2];

#define LOADK(BK, CC) do { \
  _Pragma("unroll") for (int j = 0; j < 2; ++j) \
    _Pragma("unroll") for (int kk = 0; kk < 2; ++kk) \
      BK[j][kk] = *(const short8*)&kbase[(long)((CC) * 32 + j * 16 + lr) * 1024 + (kk * 4 + lq) * 8]; \
} while (0)

#define QKT(S, BK) do { \
  _Pragma("unroll") for (int i = 0; i < 4; ++i) \
    _Pragma("unroll") for (int j = 0; j < 2; ++j) { \
      f32x4 z = {0.f, 0.f, 0.f, 0.f}; S[i][j] = z; } \
  _Pragma("unroll") for (int kk = 0; kk < 2; ++kk) \
    _Pragma("unroll") for (int i = 0; i < 4; ++i) \
      _Pragma("unroll") for (int j = 0; j < 2; ++j) \
        S[i][j] = __builtin_amdgcn_mfma_f32_16x16x32_bf16(aq[i][kk], BK[j][kk], S[i][j], 0, 0, 0); \
} while (0)

#define SOFTPV(S, CC) do { \
  short8 av_[4]; \
  _Pragma("unroll") for (int ct = 0; ct < 4; ++ct) { \
    int frow = ct * 16 + lr; \
    av_[ct] = *(const short8*)&v_t[frow * 256 + ((((CC) * 4 + lq) ^ (frow & 7)) << 3)]; } \
  float p0[4], p1[4]; \
  _Pragma("unroll") for (int i = 0; i < 4; ++i) { \
    p0[i] = fmaxf(fmaxf(S[i][0][0], S[i][0][1]), fmaxf(S[i][0][2], S[i][0][3])); \
    p1[i] = fmaxf(fmaxf(S[i][1][0], S[i][1][1]), fmaxf(S[i][1][2], S[i][1][3])); \
  } \
  float c0 = fmaxf(fmaxf(p0[0], p0[1]), fmaxf(p0[2], p0[3])); \
  float c1 = fmaxf(fmaxf(p1[0], p1[1]), fmaxf(p1[2], p1[3])); \
  c0 = fmaxf(c0, __shfl_xor(c0, 16)); c0 = fmaxf(c0, __shfl_xor(c0, 32)); \
  c1 = fmaxf(c1, __shfl_xor(c1, 16)); c1 = fmaxf(c1, __shfl_xor(c1, 32)); \
  _Pragma("unroll") for (int uu = 0; uu < 4; ++uu) { \
    _Pragma("unroll") for (int r = 0; r < 4; ++r) { \
      int qq = uu * 16 + lq * 4 + r; \
      wsl[qq][lr] = pack_hu(__expf(S[uu][0][r] - c0), __expf(S[uu][1][r] - c1)); } \
    short8 bw = *(const short8*)&wsl[uu * 16 + lr][lq * 4]; \
    acc_den[uu] = __builtin_amdgcn_mfma_f32_16x16x32_bf16(ones, bw, acc_den[uu], 0, 0, 0); \
    _Pragma("unroll") for (int ct = 0; ct < 4; ++ct) \
      acc_pv[uu][ct] = __builtin_amdgcn_mfma_f32_16x16x32_bf16(av_[ct], bw, acc_pv[uu][ct], 0, 0, 0); \
  } \
} while (0)

  // prologue: K chunks 0,1 in regs; scores for chunk 0
  LOADK(bk0, 0);
  LOADK(bk1, 1);
  QKT(sA, bk0);

  // 2-deep pipeline, unrolled (named banks; no runtime indexing)
  LOADK(bk0, 2); QKT(sB, bk1); SOFTPV(sA, 0);
  LOADK(bk1, 3); QKT(sA, bk0); SOFTPV(sB, 1);
  LOADK(bk0, 4); QKT(sB, bk1); SOFTPV(sA, 2);
  LOADK(bk1, 5); QKT(sA, bk0); SOFTPV(sB, 3);
  LOADK(bk0, 6); QKT(sB, bk1); SOFTPV(sA, 4);
  LOADK(bk1, 7); QKT(sA, bk0); SOFTPV(sB, 5);
                 QKT(sB, bk1); SOFTPV(sA, 6);
                               SOFTPV(sB, 7);

  // ---- epilogue: out[q][f] = num/den, packed 8B stores
#pragma unroll
  for (int qi = 0; qi < 4; ++qi) {
    float inv = 1.0f / (acc_den[qi][0] + 1e-10f);
    long orow = (qrow0 + qi * 16 + lr) * 1024 + hc;
#pragma unroll
    for (int ct = 0; ct < 4; ++ct) {
      uint2 p;
      p.x = pack_hu(acc_pv[qi][ct][0] * inv, acc_pv[qi][ct][1] * inv);
      p.y = pack_hu(acc_pv[qi][ct][2] * inv, acc_pv[qi][ct][3] * inv);
      *(uint2*)&attout[orow + ct * 16 + lq * 4] = p;
    }
  }
}

extern "C" void kernel_launch(void* const* d_in, const int* in_sizes, int n_in,
                              void* d_out, int out_size, void* d_ws, size_t ws_size,
                              hipStream_t stream) {
  (void)in_sizes; (void)n_in; (void)out_size; (void)ws_size;
  const float* x    = (const float*)d_in[0];
  const float* Wqkv = (const float*)d_in[1];
  const float* Wout = (const float*)d_in[2];
  float* out = (float*)d_out;
  char* ws = (char*)d_ws;

  // workspace layout (80 MB). xb aliases attout: xb is dead before attn writes.
  unsigned short* xb     = (unsigned short*)(ws);               // 33,554,432 B
  unsigned short* attout = (unsigned short*)(ws);               // (same region)
  unsigned short* wqkvb  = (unsigned short*)(ws + 33554432);    //  6,291,456 B
  unsigned short* woutb  = (unsigned short*)(ws + 39845888);    //  2,097,152 B
  unsigned short* qbuf   = (unsigned short*)(ws + 41943040);    // 33,554,432 B
  unsigned short* kbuf   = (unsigned short*)(ws + 75497472);    //  4,194,304 B
  unsigned short* vtb    = (unsigned short*)(ws + 79691776);    //  4,194,304 B

  // one merged conversion launch: x (16.7M) + Wqkv (3.1M) + Wout (1.0M)
  cvt_all<<<20480, 256, 0, stream>>>(x, Wqkv, Wout, xb, wqkvb, woutb);

  // Q = (x @ Wq^T) * hd^-0.5  -> qbuf (8-phase 256^2)
  gemm8p<false><<<dim3(64, 4), 512, 0, stream>>>(xb, wqkvb, (void*)qbuf, 0.125f);
  // K,V at dilated rows (every 8th): K -> kbuf [2048][1024], V -> vtb (sigma V^T)
  gemm_bt<2><<<dim3(16, 16), 256, 0, stream>>>(
      xb, wqkvb + 1024 * 1024, (void*)kbuf, vtb, 1.0f, 8192, 1024, 1024);

  attn_kernel<<<512, 512, 0, stream>>>(qbuf, kbuf, vtb, attout);

  // final projection: out = attout @ Wout^T (f32 output, 8-phase 256^2)
  gemm8p<true><<<dim3(64, 4), 512, 0, stream>>>(attout, woutb, (void*)out, 1.0f);
}